// Round 5
// baseline (14094.569 us; speedup 1.0000x reference)
//
#include <hip/hip_runtime.h>
#include <math.h>

#define BATCH 32
#define TLEN  4096
#define DIM   64
#define NHASH 8
#define NBUCK 64   // n_buckets
#define BSIZE 64   // bucket size

typedef __attribute__((ext_vector_type(8))) short short8;
typedef __attribute__((ext_vector_type(4))) float float4v;

__device__ inline unsigned short bf16_rne(float x) {
  unsigned u = __float_as_uint(x);
  u += 0x7FFFu + ((u >> 16) & 1u);
  return (unsigned short)(u >> 16);
}
__device__ inline float bf16_to_f32(unsigned short h) {
  return __uint_as_float(((unsigned)h) << 16);
}
// split two float4 (8 consecutive f32) into bf16 hi + lo (residual) fragments
__device__ inline void split8(const float4 a, const float4 b, short8& h, short8& l) {
  float v[8] = {a.x, a.y, a.z, a.w, b.x, b.y, b.z, b.w};
#pragma unroll
  for (int j = 0; j < 8; ++j) {
    unsigned short hb = bf16_rne(v[j]);
    h[j] = (short)hb;
    l[j] = (short)bf16_rne(v[j] - bf16_to_f32(hb));
  }
}

// ---------------------------------------------------------------------------
// Hash kernel: colors[b,r,t] = argmax_n( concat(px, -px) ).
// f32 main path (broadcast LDS reads of proj), with an error-bound margin
// test; lanes whose top-2 margin < 2E recompute the candidate set in f64
// from global memory -> argmax decisions identical to a pure-f64 pass.
// ---------------------------------------------------------------------------
__global__ __launch_bounds__(256, 2)
void hash_kernel(const float* __restrict__ x, const float* __restrict__ proj,
                 int* __restrict__ buckets) {
  __shared__ float psf[64][68];   // [n][d], stride 68 f32 (16B-aligned rows)
  const int tid = threadIdx.x;
  const int r = blockIdx.y, b = blockIdx.z;
  const int t0 = blockIdx.x << 8;

  // stage proj[d, r, n] -> psf[n][d]   (proj flat: d*512 + r*64 + n)
  for (int kk = 0; kk < 16; ++kk) {
    int idx = (kk << 8) + tid;        // 4096 = 64d x 64n
    int d = idx >> 6, nn = idx & 63;
    psf[nn][d] = proj[d * 512 + r * 64 + nn];
  }
  __syncthreads();

  const int t = t0 + tid;
  const float* xr = x + ((size_t)b * TLEN + t) * DIM;
  float4 xreg[16];
  float Sx = 0.f;
#pragma unroll
  for (int g = 0; g < 16; ++g) {
    xreg[g] = ((const float4*)xr)[g];
    Sx += fabsf(xreg[g].x) + fabsf(xreg[g].y) + fabsf(xreg[g].z) + fabsf(xreg[g].w);
  }

  float acc[64];
#pragma unroll
  for (int n = 0; n < 64; ++n) {
    float a0 = 0.f, a1 = 0.f, a2 = 0.f, a3 = 0.f;
#pragma unroll
    for (int g = 0; g < 16; ++g) {
      float4 p4 = *(const float4*)&psf[n][g * 4];   // wave-uniform -> broadcast
      a0 = fmaf(xreg[g].x, p4.x, a0);
      a1 = fmaf(xreg[g].y, p4.y, a1);
      a2 = fmaf(xreg[g].z, p4.z, a2);
      a3 = fmaf(xreg[g].w, p4.w, a3);
    }
    acc[n] = (a0 + a1) + (a2 + a3);
  }

  // f32 argmax: pos half first (jnp first-occurrence tie rule); ambiguity
  // inside the error margin falls through to the exact f64 path.
  float bestv = -INFINITY; int besti = 0;
#pragma unroll
  for (int n = 0; n < 64; ++n) { if (acc[n] > bestv) { bestv = acc[n]; besti = n; } }
#pragma unroll
  for (int n = 0; n < 64; ++n) { if (-acc[n] > bestv) { bestv = -acc[n]; besti = n + 64; } }

  // margin: |f32dot - f64dot| <= 64*eps*max|p|*Sum|x|, eps=6e-8, max|p|<=6
  const float E2 = 4.6e-5f * Sx;     // = 2 * bound (safety x2 folded in)
  const float thr = bestv - E2;
  unsigned long long candP = 0ull, candN = 0ull;
  int cnt = 0;
#pragma unroll
  for (int n = 0; n < 64; ++n) {
    if (acc[n] >= thr)  { candP |= 1ull << n; cnt++; }
    if (-acc[n] >= thr) { candN |= 1ull << n; cnt++; }
  }

  int result = besti;
  if (cnt > 1) {
    // exact re-decision: f64 dots for candidates only, index-ascending
    const float* pr = proj + r * 64;
    double bd = -1e300; int bi = 0;
    unsigned long long mm = candP;
    while (mm) {
      int nn = __ffsll((long long)mm) - 1; mm &= mm - 1;
      double s = 0.0;
      for (int d = 0; d < 64; ++d) s = fma((double)xr[d], (double)pr[d * 512 + nn], s);
      if (s > bd) { bd = s; bi = nn; }
    }
    mm = candN;
    while (mm) {
      int nn = __ffsll((long long)mm) - 1; mm &= mm - 1;
      double s = 0.0;
      for (int d = 0; d < 64; ++d) s = fma((double)xr[d], (double)pr[d * 512 + nn], s);
      if (-s > bd) { bd = -s; bi = nn + 64; }
    }
    result = bi;
  }
  buckets[((size_t)b * NHASH + r) * TLEN + t] = result;
}

// ---------------------------------------------------------------------------
// Stable counting sort per (b,r) (unchanged, verified).
// ---------------------------------------------------------------------------
__global__ __launch_bounds__(64)
void sort_kernel(const int* __restrict__ buckets, int* __restrict__ sticker,
                 int* __restrict__ pos) {
  __shared__ int lhist[64][129];
  __shared__ int starts[128];
  const int lane = threadIdx.x;
  const int br = blockIdx.x;
  const int* bk = buckets + (size_t)br * TLEN;
  int* st = sticker + (size_t)br * TLEN;
  int* ps = pos ? pos + (size_t)br * TLEN : nullptr;

  for (int i = 0; i < 128; ++i) lhist[lane][i] = 0;
  __syncthreads();
  for (int i = 0; i < 64; ++i) lhist[lane][bk[lane * 64 + i]]++;
  __syncthreads();

  int tot0 = 0, tot1 = 0;
  for (int c = 0; c < 64; ++c) {
    int v0 = lhist[c][lane];      lhist[c][lane]      = tot0; tot0 += v0;
    int v1 = lhist[c][lane + 64]; lhist[c][lane + 64] = tot1; tot1 += v1;
  }
  int s0 = tot0;
  for (int off = 1; off < 64; off <<= 1) {
    int u = __shfl_up(s0, off, 64);
    if (lane >= off) s0 += u;
  }
  int total0 = __shfl(s0, 63, 64);
  int s1 = tot1;
  for (int off = 1; off < 64; off <<= 1) {
    int u = __shfl_up(s1, off, 64);
    if (lane >= off) s1 += u;
  }
  starts[lane] = s0 - tot0;
  starts[lane + 64] = s1 - tot1 + total0;
  __syncthreads();

  for (int i = 0; i < 64; ++i) {
    int e = lane * 64 + i;
    int bb = bk[e];
    int c = lhist[lane][bb];
    lhist[lane][bb] = c + 1;
    int sp = starts[bb] + c;
    st[sp] = e;
    if (ps) ps[e] = sp;
  }
}

// ---------------------------------------------------------------------------
// MFMA attention per (bucket n, r, b_local): 64 Q rows x 128 keys, D=64.
// bf16x3 QK^T (Qh*Kh + Qh*Kl + Ql*Kh), softmax in f32, P split hi/lo,
// PV = Ph*V + Pl*V with V single bf16 (transposed in LDS).
// LDS: Khi/Klo 128x64 bf16 (XOR-swizzled 16B granules), Vt 64x128 bf16.
// P_hi/P_lo reuse the Khi/Klo regions after the QK barrier (exact fit).
// 4 waves; wave w computes Q rows [16w,16w+16). Output in sorted order.
// ---------------------------------------------------------------------------
__global__ __launch_bounds__(256, 2)
void attn_kernel(const float* __restrict__ q, const float* __restrict__ k,
                 const float* __restrict__ v,
                 const int* __restrict__ sticker_q, const int* __restrict__ sticker_k,
                 float* __restrict__ so_buf, float* __restrict__ slse_buf,
                 int b_off) {
  __shared__ __align__(16) unsigned short Khi[128 * 64];  // 16 KB; later P_hi (64x128)
  __shared__ __align__(16) unsigned short Klo[128 * 64];  // 16 KB; later P_lo
  __shared__ __align__(16) unsigned short VtS[64 * 128];  // 16 KB, Vt[d][key]

  const int tid = threadIdx.x;
  const int w = tid >> 6;          // wave 0..3
  const int l = tid & 63;
  const int l15 = l & 15;
  const int qd = l >> 4;           // quad16 group 0..3
  const int n = blockIdx.x, r = blockIdx.y, bl = blockIdx.z;
  const int b = b_off + bl;
  const size_t brbase = ((size_t)b * NHASH + r) * TLEN;
  const size_t obase  = ((size_t)bl * NHASH + r) * TLEN;
  const int nprev = (n + NBUCK - 1) & (NBUCK - 1);

  const float* kb = k + (size_t)b * TLEN * DIM;
  const float* vb = v + (size_t)b * TLEN * DIM;
  const float* qb = q + (size_t)b * TLEN * DIM;

  // ---- stage K (hi/lo, row-major, granule-swizzled) ----
  for (int it = 0; it < 4; ++it) {
    int idx = it * 256 + tid;         // 1024 = 128 rows x 8 chunks(8 f32)
    int row = idx >> 3, gc = idx & 7;
    int srow = (row < 64) ? (nprev * 64 + row) : (n * 64 + (row - 64));
    int ik = sticker_k[brbase + srow];
    const float* src = kb + (size_t)ik * DIM + gc * 8;
    short8 h8, l8;
    split8(*(const float4*)src, *(const float4*)(src + 4), h8, l8);
    int o = (row << 6) + ((gc ^ (row & 7)) << 3);
    *(short8*)&Khi[o] = h8;
    *(short8*)&Klo[o] = l8;
  }
  // ---- stage V transposed: Vt[d][key], hi only ----
  for (int it = 0; it < 8; ++it) {
    int idx = it * 256 + tid;         // 2048 = 128 keys x 16 float4
    int key = idx >> 4, g4 = idx & 15;
    int srow = (key < 64) ? (nprev * 64 + key) : (n * 64 + (key - 64));
    int ik = sticker_k[brbase + srow];
    float4 vv = *(const float4*)(vb + (size_t)ik * DIM + g4 * 4);
    int kg = key >> 3, kr = key & 7;
#pragma unroll
    for (int e = 0; e < 4; ++e) {
      int d = g4 * 4 + e;
      float val = (e == 0) ? vv.x : (e == 1) ? vv.y : (e == 2) ? vv.z : vv.w;
      VtS[d * 128 + ((kg ^ (d & 15)) << 3) + kr] = bf16_rne(val);
    }
  }

  // ---- Q fragments from global (A-layout: m=l15, k=qd*8+j), scaled by 1/8 ----
  const int torig = sticker_q[brbase + n * 64 + w * 16 + l15];
  short8 Ahi[2], Alo[2];
#pragma unroll
  for (int ks = 0; ks < 2; ++ks) {
    const float* src = qb + (size_t)torig * DIM + ks * 32 + qd * 8;
    float4 q0 = *(const float4*)src;
    float4 q1 = *(const float4*)(src + 4);
    const float sc = 0.125f;
    q0.x *= sc; q0.y *= sc; q0.z *= sc; q0.w *= sc;
    q1.x *= sc; q1.y *= sc; q1.z *= sc; q1.w *= sc;
    split8(q0, q1, Ahi[ks], Alo[ks]);
  }
  __syncthreads();

  // ---- QK^T: S[16 x 128] per wave, bf16x3 ----
  float4v Sacc[8];
#pragma unroll
  for (int nt = 0; nt < 8; ++nt) {
    float4v z = {0.f, 0.f, 0.f, 0.f};
    Sacc[nt] = z;
#pragma unroll
    for (int ks = 0; ks < 2; ++ks) {
      int key = nt * 16 + l15;
      int gk = ks * 4 + qd;                       // granule 0..7
      int o = (key << 6) + ((gk ^ (key & 7)) << 3);
      short8 Bh = *(const short8*)&Khi[o];
      short8 Bl = *(const short8*)&Klo[o];
      Sacc[nt] = __builtin_amdgcn_mfma_f32_16x16x32_bf16(Ahi[ks], Bh, Sacc[nt], 0, 0, 0);
      Sacc[nt] = __builtin_amdgcn_mfma_f32_16x16x32_bf16(Alo[ks], Bh, Sacc[nt], 0, 0, 0);
      Sacc[nt] = __builtin_amdgcn_mfma_f32_16x16x32_bf16(Ahi[ks], Bl, Sacc[nt], 0, 0, 0);
    }
  }

  // ---- softmax over 128 cols; row = qd*4+i, col = nt*16 + l15 ----
  float lsev[4];
#pragma unroll
  for (int i = 0; i < 4; ++i) {
    float m = -INFINITY;
#pragma unroll
    for (int nt = 0; nt < 8; ++nt) m = fmaxf(m, Sacc[nt][i]);
    m = fmaxf(m, __shfl_xor(m, 1, 64));
    m = fmaxf(m, __shfl_xor(m, 2, 64));
    m = fmaxf(m, __shfl_xor(m, 4, 64));
    m = fmaxf(m, __shfl_xor(m, 8, 64));
    float Z = 0.f;
#pragma unroll
    for (int nt = 0; nt < 8; ++nt) {
      float e = __expf(Sacc[nt][i] - m);
      Sacc[nt][i] = e;
      Z += e;
    }
    Z += __shfl_xor(Z, 1, 64);
    Z += __shfl_xor(Z, 2, 64);
    Z += __shfl_xor(Z, 4, 64);
    Z += __shfl_xor(Z, 8, 64);
    float invZ = 1.0f / Z;
#pragma unroll
    for (int nt = 0; nt < 8; ++nt) Sacc[nt][i] *= invZ;
    lsev[i] = m + __logf(Z);
  }
  if (l15 == 0) {
#pragma unroll
    for (int i = 0; i < 4; ++i)
      slse_buf[brbase + n * 64 + w * 16 + qd * 4 + i] = lsev[i];
  }

  __syncthreads();   // all waves done reading Khi/Klo before P overwrites them

  // ---- write P (hi/lo) to LDS, 64 rows x 128 cols, granule-swizzled ----
  unsigned short* Phi = Khi;
  unsigned short* Plo = Klo;
#pragma unroll
  for (int nt = 0; nt < 8; ++nt) {
#pragma unroll
    for (int i = 0; i < 4; ++i) {
      int prow = w * 16 + qd * 4 + i;
      int col = nt * 16 + l15;
      float pv = Sacc[nt][i];
      unsigned short ph = bf16_rne(pv);
      unsigned short pl = bf16_rne(pv - bf16_to_f32(ph));
      int o = prow * 128 + (((col >> 3) ^ (prow & 15)) << 3) + (col & 7);
      Phi[o] = ph;
      Plo[o] = pl;
    }
  }
  // own-wave write->read (each wave reads only rows it wrote; DS ops in order)

  // ---- PV: O[16 x 64] per wave ----
  float4v Oacc[4];
#pragma unroll
  for (int dt = 0; dt < 4; ++dt) { float4v z = {0.f, 0.f, 0.f, 0.f}; Oacc[dt] = z; }
#pragma unroll
  for (int ks = 0; ks < 4; ++ks) {
    int arow = w * 16 + l15;
    int ga = (ks * 4 + qd) ^ (arow & 15);
    int ao = arow * 128 + (ga << 3);
    short8 Ph = *(const short8*)&Phi[ao];
    short8 Pl = *(const short8*)&Plo[ao];
#pragma unroll
    for (int dt = 0; dt < 4; ++dt) {
      int vrow = dt * 16 + l15;
      int gv = (ks * 4 + qd) ^ (vrow & 15);
      short8 Bv = *(const short8*)&VtS[vrow * 128 + (gv << 3)];
      Oacc[dt] = __builtin_amdgcn_mfma_f32_16x16x32_bf16(Ph, Bv, Oacc[dt], 0, 0, 0);
      Oacc[dt] = __builtin_amdgcn_mfma_f32_16x16x32_bf16(Pl, Bv, Oacc[dt], 0, 0, 0);
    }
  }

  // ---- epilogue: sorted-order store. D[row=qd*4+i][col=l15] per dt ----
#pragma unroll
  for (int dt = 0; dt < 4; ++dt) {
#pragma unroll
    for (int i = 0; i < 4; ++i) {
      int orow = n * 64 + w * 16 + qd * 4 + i;
      so_buf[(obase + orow) * DIM + dt * 16 + l15] = Oacc[dt][i];
    }
  }
}

// ---------------------------------------------------------------------------
// Combine the 8 hash rounds (gather via pos_q; unchanged, verified).
// ---------------------------------------------------------------------------
__global__ __launch_bounds__(256)
void combine_kernel(const float* __restrict__ so_buf, const float* __restrict__ slse_buf,
                    const int* __restrict__ pos_q, float* __restrict__ out, int b_off) {
  const size_t tid = (size_t)blockIdx.x * 256 + threadIdx.x;
  const size_t bt = tid >> 4;
  const int g = (int)(tid & 15);
  const size_t bl = bt >> 12;
  const size_t t = bt & 4095;
  const size_t b = b_off + bl;

  int pp[8];
  float l[8];
  float M = -INFINITY;
#pragma unroll
  for (int rr = 0; rr < 8; ++rr) {
    pp[rr] = pos_q[(b * NHASH + rr) * TLEN + t];
    l[rr] = slse_buf[(b * NHASH + rr) * TLEN + pp[rr]];
    M = fmaxf(M, l[rr]);
  }
  float Z = 0.f;
  float w[8];
#pragma unroll
  for (int rr = 0; rr < 8; ++rr) { w[rr] = __expf(l[rr] - M); Z += w[rr]; }
  const float invZ = 1.0f / Z;

  float4 s = make_float4(0.f, 0.f, 0.f, 0.f);
#pragma unroll
  for (int rr = 0; rr < 8; ++rr) {
    const float* op = so_buf + ((bl * NHASH + rr) * TLEN + (size_t)pp[rr]) * DIM + g * 4;
    float4 ov = *(const float4*)op;
    s.x = fmaf(w[rr], ov.x, s.x);
    s.y = fmaf(w[rr], ov.y, s.y);
    s.z = fmaf(w[rr], ov.z, s.z);
    s.w = fmaf(w[rr], ov.w, s.w);
  }
  s.x *= invZ; s.y *= invZ; s.z *= invZ; s.w *= invZ;
  *(float4*)(out + (b * TLEN + t) * DIM + g * 4) = s;
}

// ---------------------------------------------------------------------------
// Workspace layout (adaptive): stickers 8MB + pos 4MB + slse 4MB + shared
// region (buckets during hash/sort, so_buf CB*8MB during attn/combine).
// ---------------------------------------------------------------------------
extern "C" void kernel_launch(void* const* d_in, const int* in_sizes, int n_in,
                              void* d_out, int out_size, void* d_ws, size_t ws_size,
                              hipStream_t stream) {
  const float* q = (const float*)d_in[0];
  const float* k = (const float*)d_in[1];
  const float* v = (const float*)d_in[2];
  const float* proj = (const float*)d_in[3];
  float* out = (float*)d_out;

  char* ws = (char*)d_ws;
  const size_t MB = (size_t)1 << 20;
  int* sticker_q = (int*)(ws + 0 * MB);
  int* sticker_k = (int*)(ws + 4 * MB);
  int* pos_q     = (int*)(ws + 8 * MB);
  float* slse_buf = (float*)(ws + 12 * MB);
  int* buckets_q = (int*)(ws + 16 * MB);
  int* buckets_k = (int*)(ws + 20 * MB);
  float* so_buf  = (float*)(ws + 16 * MB);

  int CB = 32;
  while (CB > 1 && 16 * MB + (size_t)CB * 8 * MB > ws_size) CB >>= 1;

  hash_kernel<<<dim3(TLEN / 256, NHASH, BATCH), 256, 0, stream>>>(q, proj, buckets_q);
  hash_kernel<<<dim3(TLEN / 256, NHASH, BATCH), 256, 0, stream>>>(k, proj, buckets_k);
  sort_kernel<<<dim3(BATCH * NHASH), 64, 0, stream>>>(buckets_q, sticker_q, pos_q);
  sort_kernel<<<dim3(BATCH * NHASH), 64, 0, stream>>>(buckets_k, sticker_k, nullptr);

  for (int b_off = 0; b_off < BATCH; b_off += CB) {
    attn_kernel<<<dim3(NBUCK, NHASH, CB), 256, 0, stream>>>(
        q, k, v, sticker_q, sticker_k, so_buf, slse_buf, b_off);
    combine_kernel<<<dim3(CB * TLEN * 16 / 256), 256, 0, stream>>>(
        so_buf, slse_buf, pos_q, out, b_off);
  }
}

// Round 6
// 988.761 us; speedup vs baseline: 14.2548x; 14.2548x over previous
//
#include <hip/hip_runtime.h>
#include <math.h>

#define BATCH 32
#define TLEN  4096
#define DIM   64
#define NHASH 8
#define NBUCK 64   // n_buckets
#define BSIZE 64   // bucket size

typedef __attribute__((ext_vector_type(8))) short short8;
typedef __attribute__((ext_vector_type(4))) float float4v;

__device__ inline unsigned short bf16_rne(float x) {
  unsigned u = __float_as_uint(x);
  u += 0x7FFFu + ((u >> 16) & 1u);
  return (unsigned short)(u >> 16);
}
__device__ inline float bf16_to_f32(unsigned short h) {
  return __uint_as_float(((unsigned)h) << 16);
}
// split two float4 (8 consecutive f32) into bf16 hi + lo (residual) fragments
__device__ inline void split8(const float4 a, const float4 b, short8& h, short8& l) {
  float v[8] = {a.x, a.y, a.z, a.w, b.x, b.y, b.z, b.w};
#pragma unroll
  for (int j = 0; j < 8; ++j) {
    unsigned short hb = bf16_rne(v[j]);
    h[j] = (short)hb;
    l[j] = (short)bf16_rne(v[j] - bf16_to_f32(hb));
  }
}

// ---------------------------------------------------------------------------
// Hash kernel: colors[b,r,t] = argmax_n( concat(px, -px) ).
// STREAMING f32 main path: no acc[64] array (round-5 post-mortem: 64 live
// accumulators + 64-reg x tile forced a scratch spill -> 23 GB HBM traffic).
// Track best/second-best only; if the top-2 gap is inside the rigorous f32
// error bound, recompute ALL 128 colors in f64 (exact: psf is an exact f32
// copy of proj; xreg exact) using the verified round-2 comparison order.
// ---------------------------------------------------------------------------
__global__ __launch_bounds__(256, 2)
void hash_kernel(const float* __restrict__ x, const float* __restrict__ proj,
                 int* __restrict__ buckets) {
  __shared__ float psf[64][68];   // [n][d], stride 68 f32 (16B-aligned rows)
  const int tid = threadIdx.x;
  const int r = blockIdx.y, b = blockIdx.z;
  const int t0 = blockIdx.x << 8;

  // stage proj[d, r, n] -> psf[n][d]   (proj flat: d*512 + r*64 + n)
  for (int kk = 0; kk < 16; ++kk) {
    int idx = (kk << 8) + tid;        // 4096 = 64d x 64n
    int d = idx >> 6, nn = idx & 63;
    psf[nn][d] = proj[d * 512 + r * 64 + nn];
  }
  __syncthreads();

  const int t = t0 + tid;
  const float* xr = x + ((size_t)b * TLEN + t) * DIM;
  float4 xreg[16];
  float Sx = 0.f;
#pragma unroll
  for (int g = 0; g < 16; ++g) {
    xreg[g] = ((const float4*)xr)[g];
    Sx += fabsf(xreg[g].x) + fabsf(xreg[g].y) + fabsf(xreg[g].z) + fabsf(xreg[g].w);
  }

  // streaming argmax over 128 candidates (pos,neg interleaved per n);
  // any ordering ambiguity vs the concat order is covered by the margin test.
  float bestv = -INFINITY, sb = -INFINITY;
  int besti = 0;
  for (int n = 0; n < 64; ++n) {
    float a0 = 0.f, a1 = 0.f, a2 = 0.f, a3 = 0.f;
#pragma unroll
    for (int g = 0; g < 16; ++g) {
      float4 p4 = *(const float4*)&psf[n][g * 4];   // wave-uniform -> broadcast
      a0 = fmaf(xreg[g].x, p4.x, a0);
      a1 = fmaf(xreg[g].y, p4.y, a1);
      a2 = fmaf(xreg[g].z, p4.z, a2);
      a3 = fmaf(xreg[g].w, p4.w, a3);
    }
    float acc = (a0 + a1) + (a2 + a3);
    if (acc > bestv)      { sb = bestv; bestv = acc;  besti = n; }
    else if (acc > sb)    { sb = acc; }
    float negacc = -acc;
    if (negacc > bestv)   { sb = bestv; bestv = negacc; besti = n + 64; }
    else if (negacc > sb) { sb = negacc; }
  }

  int result = besti;
  // margin: |f32dot - f64dot| <= 64*eps*max|p|*Sum|x|; x2 for two operands
  const float E2 = 4.6e-5f * Sx;
  if (bestv - sb < E2) {
    // exact f64 re-decision over all 128, concat order semantics
    double bestp = -1e300, bestn = -1e300;
    int idxp = 0, idxn = 0;
    for (int n = 0; n < 64; ++n) {
      double a0 = 0.0, a1 = 0.0, a2 = 0.0, a3 = 0.0;
#pragma unroll
      for (int g = 0; g < 16; ++g) {
        float4 p4 = *(const float4*)&psf[n][g * 4];
        a0 = fma((double)xreg[g].x, (double)p4.x, a0);
        a1 = fma((double)xreg[g].y, (double)p4.y, a1);
        a2 = fma((double)xreg[g].z, (double)p4.z, a2);
        a3 = fma((double)xreg[g].w, (double)p4.w, a3);
      }
      double acc = (a0 + a1) + (a2 + a3);
      if (acc > bestp)  { bestp = acc;  idxp = n; }
      if (-acc > bestn) { bestn = -acc; idxn = n; }
    }
    result = (bestp >= bestn) ? idxp : (idxn + 64);
  }
  buckets[((size_t)b * NHASH + r) * TLEN + t] = result;
}

// ---------------------------------------------------------------------------
// Stable counting sort per (b,r) (unchanged, verified).
// ---------------------------------------------------------------------------
__global__ __launch_bounds__(64)
void sort_kernel(const int* __restrict__ buckets, int* __restrict__ sticker,
                 int* __restrict__ pos) {
  __shared__ int lhist[64][129];
  __shared__ int starts[128];
  const int lane = threadIdx.x;
  const int br = blockIdx.x;
  const int* bk = buckets + (size_t)br * TLEN;
  int* st = sticker + (size_t)br * TLEN;
  int* ps = pos ? pos + (size_t)br * TLEN : nullptr;

  for (int i = 0; i < 128; ++i) lhist[lane][i] = 0;
  __syncthreads();
  for (int i = 0; i < 64; ++i) lhist[lane][bk[lane * 64 + i]]++;
  __syncthreads();

  int tot0 = 0, tot1 = 0;
  for (int c = 0; c < 64; ++c) {
    int v0 = lhist[c][lane];      lhist[c][lane]      = tot0; tot0 += v0;
    int v1 = lhist[c][lane + 64]; lhist[c][lane + 64] = tot1; tot1 += v1;
  }
  int s0 = tot0;
  for (int off = 1; off < 64; off <<= 1) {
    int u = __shfl_up(s0, off, 64);
    if (lane >= off) s0 += u;
  }
  int total0 = __shfl(s0, 63, 64);
  int s1 = tot1;
  for (int off = 1; off < 64; off <<= 1) {
    int u = __shfl_up(s1, off, 64);
    if (lane >= off) s1 += u;
  }
  starts[lane] = s0 - tot0;
  starts[lane + 64] = s1 - tot1 + total0;
  __syncthreads();

  for (int i = 0; i < 64; ++i) {
    int e = lane * 64 + i;
    int bb = bk[e];
    int c = lhist[lane][bb];
    lhist[lane][bb] = c + 1;
    int sp = starts[bb] + c;
    st[sp] = e;
    if (ps) ps[e] = sp;
  }
}

// ---------------------------------------------------------------------------
// MFMA attention per (bucket n, r, b_local): 64 Q rows x 128 keys, D=64.
// bf16x3 QK^T (Qh*Kh + Qh*Kl + Ql*Kh), softmax in f32, P split hi/lo,
// PV = Ph*V + Pl*V with V single bf16 (transposed in LDS).
// Verified round 5 (absmax 3.9e-3). Unchanged.
// ---------------------------------------------------------------------------
__global__ __launch_bounds__(256, 2)
void attn_kernel(const float* __restrict__ q, const float* __restrict__ k,
                 const float* __restrict__ v,
                 const int* __restrict__ sticker_q, const int* __restrict__ sticker_k,
                 float* __restrict__ so_buf, float* __restrict__ slse_buf,
                 int b_off) {
  __shared__ __align__(16) unsigned short Khi[128 * 64];  // 16 KB; later P_hi (64x128)
  __shared__ __align__(16) unsigned short Klo[128 * 64];  // 16 KB; later P_lo
  __shared__ __align__(16) unsigned short VtS[64 * 128];  // 16 KB, Vt[d][key]

  const int tid = threadIdx.x;
  const int w = tid >> 6;          // wave 0..3
  const int l = tid & 63;
  const int l15 = l & 15;
  const int qd = l >> 4;           // quad16 group 0..3
  const int n = blockIdx.x, r = blockIdx.y, bl = blockIdx.z;
  const int b = b_off + bl;
  const size_t brbase = ((size_t)b * NHASH + r) * TLEN;
  const size_t obase  = ((size_t)bl * NHASH + r) * TLEN;
  const int nprev = (n + NBUCK - 1) & (NBUCK - 1);

  const float* kb = k + (size_t)b * TLEN * DIM;
  const float* vb = v + (size_t)b * TLEN * DIM;
  const float* qb = q + (size_t)b * TLEN * DIM;

  // ---- stage K (hi/lo, row-major, granule-swizzled) ----
  for (int it = 0; it < 4; ++it) {
    int idx = it * 256 + tid;         // 1024 = 128 rows x 8 chunks(8 f32)
    int row = idx >> 3, gc = idx & 7;
    int srow = (row < 64) ? (nprev * 64 + row) : (n * 64 + (row - 64));
    int ik = sticker_k[brbase + srow];
    const float* src = kb + (size_t)ik * DIM + gc * 8;
    short8 h8, l8;
    split8(*(const float4*)src, *(const float4*)(src + 4), h8, l8);
    int o = (row << 6) + ((gc ^ (row & 7)) << 3);
    *(short8*)&Khi[o] = h8;
    *(short8*)&Klo[o] = l8;
  }
  // ---- stage V transposed: Vt[d][key], hi only ----
  for (int it = 0; it < 8; ++it) {
    int idx = it * 256 + tid;         // 2048 = 128 keys x 16 float4
    int key = idx >> 4, g4 = idx & 15;
    int srow = (key < 64) ? (nprev * 64 + key) : (n * 64 + (key - 64));
    int ik = sticker_k[brbase + srow];
    float4 vv = *(const float4*)(vb + (size_t)ik * DIM + g4 * 4);
    int kg = key >> 3, kr = key & 7;
#pragma unroll
    for (int e = 0; e < 4; ++e) {
      int d = g4 * 4 + e;
      float val = (e == 0) ? vv.x : (e == 1) ? vv.y : (e == 2) ? vv.z : vv.w;
      VtS[d * 128 + ((kg ^ (d & 15)) << 3) + kr] = bf16_rne(val);
    }
  }

  // ---- Q fragments from global (A-layout: m=l15, k=qd*8+j), scaled by 1/8 ----
  const int torig = sticker_q[brbase + n * 64 + w * 16 + l15];
  short8 Ahi[2], Alo[2];
#pragma unroll
  for (int ks = 0; ks < 2; ++ks) {
    const float* src = qb + (size_t)torig * DIM + ks * 32 + qd * 8;
    float4 q0 = *(const float4*)src;
    float4 q1 = *(const float4*)(src + 4);
    const float sc = 0.125f;
    q0.x *= sc; q0.y *= sc; q0.z *= sc; q0.w *= sc;
    q1.x *= sc; q1.y *= sc; q1.z *= sc; q1.w *= sc;
    split8(q0, q1, Ahi[ks], Alo[ks]);
  }
  __syncthreads();

  // ---- QK^T: S[16 x 128] per wave, bf16x3 ----
  float4v Sacc[8];
#pragma unroll
  for (int nt = 0; nt < 8; ++nt) {
    float4v z = {0.f, 0.f, 0.f, 0.f};
    Sacc[nt] = z;
#pragma unroll
    for (int ks = 0; ks < 2; ++ks) {
      int key = nt * 16 + l15;
      int gk = ks * 4 + qd;                       // granule 0..7
      int o = (key << 6) + ((gk ^ (key & 7)) << 3);
      short8 Bh = *(const short8*)&Khi[o];
      short8 Bl = *(const short8*)&Klo[o];
      Sacc[nt] = __builtin_amdgcn_mfma_f32_16x16x32_bf16(Ahi[ks], Bh, Sacc[nt], 0, 0, 0);
      Sacc[nt] = __builtin_amdgcn_mfma_f32_16x16x32_bf16(Alo[ks], Bh, Sacc[nt], 0, 0, 0);
      Sacc[nt] = __builtin_amdgcn_mfma_f32_16x16x32_bf16(Ahi[ks], Bl, Sacc[nt], 0, 0, 0);
    }
  }

  // ---- softmax over 128 cols; row = qd*4+i, col = nt*16 + l15 ----
  float lsev[4];
#pragma unroll
  for (int i = 0; i < 4; ++i) {
    float m = -INFINITY;
#pragma unroll
    for (int nt = 0; nt < 8; ++nt) m = fmaxf(m, Sacc[nt][i]);
    m = fmaxf(m, __shfl_xor(m, 1, 64));
    m = fmaxf(m, __shfl_xor(m, 2, 64));
    m = fmaxf(m, __shfl_xor(m, 4, 64));
    m = fmaxf(m, __shfl_xor(m, 8, 64));
    float Z = 0.f;
#pragma unroll
    for (int nt = 0; nt < 8; ++nt) {
      float e = __expf(Sacc[nt][i] - m);
      Sacc[nt][i] = e;
      Z += e;
    }
    Z += __shfl_xor(Z, 1, 64);
    Z += __shfl_xor(Z, 2, 64);
    Z += __shfl_xor(Z, 4, 64);
    Z += __shfl_xor(Z, 8, 64);
    float invZ = 1.0f / Z;
#pragma unroll
    for (int nt = 0; nt < 8; ++nt) Sacc[nt][i] *= invZ;
    lsev[i] = m + __logf(Z);
  }
  if (l15 == 0) {
#pragma unroll
    for (int i = 0; i < 4; ++i)
      slse_buf[brbase + n * 64 + w * 16 + qd * 4 + i] = lsev[i];
  }

  __syncthreads();   // all waves done reading Khi/Klo before P overwrites them

  // ---- write P (hi/lo) to LDS, 64 rows x 128 cols, granule-swizzled ----
  unsigned short* Phi = Khi;
  unsigned short* Plo = Klo;
#pragma unroll
  for (int nt = 0; nt < 8; ++nt) {
#pragma unroll
    for (int i = 0; i < 4; ++i) {
      int prow = w * 16 + qd * 4 + i;
      int col = nt * 16 + l15;
      float pv = Sacc[nt][i];
      unsigned short ph = bf16_rne(pv);
      unsigned short pl = bf16_rne(pv - bf16_to_f32(ph));
      int o = prow * 128 + (((col >> 3) ^ (prow & 15)) << 3) + (col & 7);
      Phi[o] = ph;
      Plo[o] = pl;
    }
  }
  // own-wave write->read (each wave reads only rows it wrote; DS ops in order)

  // ---- PV: O[16 x 64] per wave ----
  float4v Oacc[4];
#pragma unroll
  for (int dt = 0; dt < 4; ++dt) { float4v z = {0.f, 0.f, 0.f, 0.f}; Oacc[dt] = z; }
#pragma unroll
  for (int ks = 0; ks < 4; ++ks) {
    int arow = w * 16 + l15;
    int ga = (ks * 4 + qd) ^ (arow & 15);
    int ao = arow * 128 + (ga << 3);
    short8 Ph = *(const short8*)&Phi[ao];
    short8 Pl = *(const short8*)&Plo[ao];
#pragma unroll
    for (int dt = 0; dt < 4; ++dt) {
      int vrow = dt * 16 + l15;
      int gv = (ks * 4 + qd) ^ (vrow & 15);
      short8 Bv = *(const short8*)&VtS[vrow * 128 + (gv << 3)];
      Oacc[dt] = __builtin_amdgcn_mfma_f32_16x16x32_bf16(Ph, Bv, Oacc[dt], 0, 0, 0);
      Oacc[dt] = __builtin_amdgcn_mfma_f32_16x16x32_bf16(Pl, Bv, Oacc[dt], 0, 0, 0);
    }
  }

  // ---- epilogue: sorted-order store. D[row=qd*4+i][col=l15] per dt ----
#pragma unroll
  for (int dt = 0; dt < 4; ++dt) {
#pragma unroll
    for (int i = 0; i < 4; ++i) {
      int orow = n * 64 + w * 16 + qd * 4 + i;
      so_buf[(obase + orow) * DIM + dt * 16 + l15] = Oacc[dt][i];
    }
  }
}

// ---------------------------------------------------------------------------
// Combine the 8 hash rounds (gather via pos_q; unchanged, verified).
// ---------------------------------------------------------------------------
__global__ __launch_bounds__(256)
void combine_kernel(const float* __restrict__ so_buf, const float* __restrict__ slse_buf,
                    const int* __restrict__ pos_q, float* __restrict__ out, int b_off) {
  const size_t tid = (size_t)blockIdx.x * 256 + threadIdx.x;
  const size_t bt = tid >> 4;
  const int g = (int)(tid & 15);
  const size_t bl = bt >> 12;
  const size_t t = bt & 4095;
  const size_t b = b_off + bl;

  int pp[8];
  float l[8];
  float M = -INFINITY;
#pragma unroll
  for (int rr = 0; rr < 8; ++rr) {
    pp[rr] = pos_q[(b * NHASH + rr) * TLEN + t];
    l[rr] = slse_buf[(b * NHASH + rr) * TLEN + pp[rr]];
    M = fmaxf(M, l[rr]);
  }
  float Z = 0.f;
  float w[8];
#pragma unroll
  for (int rr = 0; rr < 8; ++rr) { w[rr] = __expf(l[rr] - M); Z += w[rr]; }
  const float invZ = 1.0f / Z;

  float4 s = make_float4(0.f, 0.f, 0.f, 0.f);
#pragma unroll
  for (int rr = 0; rr < 8; ++rr) {
    const float* op = so_buf + ((bl * NHASH + rr) * TLEN + (size_t)pp[rr]) * DIM + g * 4;
    float4 ov = *(const float4*)op;
    s.x = fmaf(w[rr], ov.x, s.x);
    s.y = fmaf(w[rr], ov.y, s.y);
    s.z = fmaf(w[rr], ov.z, s.z);
    s.w = fmaf(w[rr], ov.w, s.w);
  }
  s.x *= invZ; s.y *= invZ; s.z *= invZ; s.w *= invZ;
  *(float4*)(out + (b * TLEN + t) * DIM + g * 4) = s;
}

// ---------------------------------------------------------------------------
// Workspace layout (adaptive): stickers 8MB + pos 4MB + slse 4MB + shared
// region (buckets during hash/sort, so_buf CB*8MB during attn/combine).
// ---------------------------------------------------------------------------
extern "C" void kernel_launch(void* const* d_in, const int* in_sizes, int n_in,
                              void* d_out, int out_size, void* d_ws, size_t ws_size,
                              hipStream_t stream) {
  const float* q = (const float*)d_in[0];
  const float* k = (const float*)d_in[1];
  const float* v = (const float*)d_in[2];
  const float* proj = (const float*)d_in[3];
  float* out = (float*)d_out;

  char* ws = (char*)d_ws;
  const size_t MB = (size_t)1 << 20;
  int* sticker_q = (int*)(ws + 0 * MB);
  int* sticker_k = (int*)(ws + 4 * MB);
  int* pos_q     = (int*)(ws + 8 * MB);
  float* slse_buf = (float*)(ws + 12 * MB);
  int* buckets_q = (int*)(ws + 16 * MB);
  int* buckets_k = (int*)(ws + 20 * MB);
  float* so_buf  = (float*)(ws + 16 * MB);

  int CB = 32;
  while (CB > 1 && 16 * MB + (size_t)CB * 8 * MB > ws_size) CB >>= 1;

  hash_kernel<<<dim3(TLEN / 256, NHASH, BATCH), 256, 0, stream>>>(q, proj, buckets_q);
  hash_kernel<<<dim3(TLEN / 256, NHASH, BATCH), 256, 0, stream>>>(k, proj, buckets_k);
  sort_kernel<<<dim3(BATCH * NHASH), 64, 0, stream>>>(buckets_q, sticker_q, pos_q);
  sort_kernel<<<dim3(BATCH * NHASH), 64, 0, stream>>>(buckets_k, sticker_k, nullptr);

  for (int b_off = 0; b_off < BATCH; b_off += CB) {
    attn_kernel<<<dim3(NBUCK, NHASH, CB), 256, 0, stream>>>(
        q, k, v, sticker_q, sticker_k, so_buf, slse_buf, b_off);
    combine_kernel<<<dim3(CB * TLEN * 16 / 256), 256, 0, stream>>>(
        so_buf, slse_buf, pos_q, out, b_off);
  }
}

// Round 7
// 815.554 us; speedup vs baseline: 17.2822x; 1.2124x over previous
//
#include <hip/hip_runtime.h>
#include <math.h>

#define BATCH 32
#define TLEN  4096
#define DIM   64
#define NHASH 8
#define NBUCK 64   // n_buckets
#define BSIZE 64   // bucket size

typedef __attribute__((ext_vector_type(8))) short short8;
typedef __attribute__((ext_vector_type(4))) float float4v;

__device__ inline unsigned short bf16_rne(float x) {
  unsigned u = __float_as_uint(x);
  u += 0x7FFFu + ((u >> 16) & 1u);
  return (unsigned short)(u >> 16);
}
__device__ inline float bf16_to_f32(unsigned short h) {
  return __uint_as_float(((unsigned)h) << 16);
}
// split two float4 (8 consecutive f32) into bf16 hi + lo (residual) fragments
__device__ inline void split8(const float4 a, const float4 b, short8& h, short8& l) {
  float v[8] = {a.x, a.y, a.z, a.w, b.x, b.y, b.z, b.w};
#pragma unroll
  for (int j = 0; j < 8; ++j) {
    unsigned short hb = bf16_rne(v[j]);
    h[j] = (short)hb;
    l[j] = (short)bf16_rne(v[j] - bf16_to_f32(hb));
  }
}

// ---------------------------------------------------------------------------
// MFMA hash kernel: colors[b,r,t] = argmax_n( concat(px, -px) ).
// Round-6 post-mortem: the vector-f32 version issued 1024 ds_read_b128/wave
// (~12 cyc each) -> LDS-issue-bound at 335 us. Here the 64x64 dot-products
// are computed with bf16x4 MFMA (Ah*Bh+Al*Bh+Ah*Bl+Al*Bl ~ f32-accurate),
// argmax via 16-lane shuffle reduction on the C-layout, and an exact f64
// COOPERATIVE fallback (16 lanes x 4 colors each) for rows whose top-2 gap
// is inside the rigorous error bound E2 = 2.5e-4 * Sum|x|. Decisions are
// bit-identical to a pure-f64 argmax.
// Block: 256 threads = 4 waves; wave w handles rows [16w, 16w+16) of a
// 64-row tile. Grid: (T/64, NHASH, BATCH).
// ---------------------------------------------------------------------------
__global__ __launch_bounds__(256, 2)
void hash_kernel(const float* __restrict__ x, const float* __restrict__ proj,
                 int* __restrict__ buckets) {
  __shared__ float psf[64][68];                        // exact f32 proj [n][d]
  __shared__ __align__(16) unsigned short pbh[64 * 64]; // bf16 hi, [n][d] swizzled
  __shared__ __align__(16) unsigned short pbl[64 * 64]; // bf16 lo
  __shared__ float sxs[64];                             // per-row Sum|x|

  const int tid = threadIdx.x;
  const int w = tid >> 6;
  const int l = tid & 63;
  const int l15 = l & 15;
  const int qd = l >> 4;
  const int r = blockIdx.y, b = blockIdx.z;
  const int t0 = blockIdx.x << 6;

  // stage proj[d, r, n] -> psf[n][d] (f32) + pbh/pbl (bf16, granule-swizzled)
  for (int kk = 0; kk < 16; ++kk) {
    int idx = (kk << 8) + tid;        // 4096 = 64d x 64n
    int d = idx >> 6, nn = idx & 63;
    float val = proj[d * 512 + r * 64 + nn];
    psf[nn][d] = val;
    unsigned short hb = bf16_rne(val);
    unsigned short lb = bf16_rne(val - bf16_to_f32(hb));
    int g = d >> 3, e = d & 7;
    int o = (nn << 6) + ((g ^ (nn & 7)) << 3) + e;
    pbh[o] = hb;
    pbl[o] = lb;
  }

  // A-fragments: lane holds x[row m=l15][k = qd*8+j] for 2 k-steps; also Sum|x|
  const int trow_a = t0 + w * 16 + l15;
  const float* xra = x + ((size_t)b * TLEN + trow_a) * DIM;
  short8 Ahi[2], Alo[2];
  float sxp = 0.f;
#pragma unroll
  for (int ks = 0; ks < 2; ++ks) {
    float4 x0 = *(const float4*)(xra + ks * 32 + qd * 8);
    float4 x1 = *(const float4*)(xra + ks * 32 + qd * 8 + 4);
    sxp += fabsf(x0.x) + fabsf(x0.y) + fabsf(x0.z) + fabsf(x0.w)
         + fabsf(x1.x) + fabsf(x1.y) + fabsf(x1.z) + fabsf(x1.w);
    split8(x0, x1, Ahi[ks], Alo[ks]);
  }
  // sum over qd (lanes l15+16*qd): xor 16, 32
  sxp += __shfl_xor(sxp, 16, 64);
  sxp += __shfl_xor(sxp, 32, 64);
  if (qd == 0) sxs[w * 16 + l15] = sxp;   // same-wave write->read (DS in order)
  __syncthreads();

  // MFMA: S[row][n], rows 16 per wave, n = nt*16 + l15, bf16x4
  float4v Sacc[4];
#pragma unroll
  for (int nt = 0; nt < 4; ++nt) {
    float4v z = {0.f, 0.f, 0.f, 0.f};
    Sacc[nt] = z;
#pragma unroll
    for (int ks = 0; ks < 2; ++ks) {
      int nn = nt * 16 + l15;
      int gk = ks * 4 + qd;
      int o = (nn << 6) + ((gk ^ (nn & 7)) << 3);
      short8 Bh = *(const short8*)&pbh[o];
      short8 Bl = *(const short8*)&pbl[o];
      Sacc[nt] = __builtin_amdgcn_mfma_f32_16x16x32_bf16(Ahi[ks], Bh, Sacc[nt], 0, 0, 0);
      Sacc[nt] = __builtin_amdgcn_mfma_f32_16x16x32_bf16(Alo[ks], Bh, Sacc[nt], 0, 0, 0);
      Sacc[nt] = __builtin_amdgcn_mfma_f32_16x16x32_bf16(Ahi[ks], Bl, Sacc[nt], 0, 0, 0);
      Sacc[nt] = __builtin_amdgcn_mfma_f32_16x16x32_bf16(Alo[ks], Bl, Sacc[nt], 0, 0, 0);
    }
  }

  // argmax per row i (C layout: row = qd*4+i, col = nt*16+l15)
#pragma unroll
  for (int i = 0; i < 4; ++i) {
    float bv = -INFINITY, sbv = -INFINITY;
    int bidx = 0;
#pragma unroll
    for (int nt = 0; nt < 4; ++nt) {
      int nn = nt * 16 + l15;
      float v = Sacc[nt][i];
      if (v > bv) { sbv = bv; bv = v; bidx = nn; }
      else        { sbv = fmaxf(sbv, v); }       // equality -> sbv==bv -> fallback
      float nv = -v;
      if (nv > bv) { sbv = bv; bv = nv; bidx = nn + 64; }
      else         { sbv = fmaxf(sbv, nv); }
    }
    // butterfly over the 16-lane col group
#pragma unroll
    for (int h = 1; h <= 8; h <<= 1) {
      float obv = __shfl_xor(bv, h, 64);
      float osb = __shfl_xor(sbv, h, 64);
      int   obi = __shfl_xor(bidx, h, 64);
      if (obv > bv)        { sbv = fmaxf(bv, osb); bv = obv; bidx = obi; }
      else if (obv == bv)  { sbv = bv; bidx = min(bidx, obi); }  // gap 0
      else                 { sbv = fmaxf(sbv, obv); }
    }
    const int trow = t0 + w * 16 + qd * 4 + i;
    const float Sx = sxs[w * 16 + qd * 4 + i];
    // group-uniform ambiguity test (bv/sbv identical across the 16 lanes)
    if (bv - sbv < 2.5e-4f * Sx) {
      // exact f64 cooperative re-decision: lane handles colors nt*16+l15
      const float* xr2 = x + ((size_t)b * TLEN + trow) * DIM;
      double db = -1e300; int dbi = 0;
#pragma unroll
      for (int nt = 0; nt < 4; ++nt) {
        int nn = nt * 16 + l15;
        double s = 0.0;
        for (int d = 0; d < 64; ++d)
          s = fma((double)xr2[d], (double)psf[nn][d], s);
        if (s > db || (s == db && nn < dbi)) { db = s; dbi = nn; }
        double ns = -s; int nsi = nn + 64;
        if (ns > db || (ns == db && nsi < dbi)) { db = ns; dbi = nsi; }
      }
#pragma unroll
      for (int h = 1; h <= 8; h <<= 1) {
        double od = __shfl_xor(db, h, 64);
        int    oi = __shfl_xor(dbi, h, 64);
        if (od > db || (od == db && oi < dbi)) { db = od; dbi = oi; }
      }
      bidx = dbi;
    }
    if (l15 == 0)
      buckets[((size_t)b * NHASH + r) * TLEN + trow] = bidx;
  }
}

// ---------------------------------------------------------------------------
// Stable counting sort per (b,r) (unchanged, verified).
// ---------------------------------------------------------------------------
__global__ __launch_bounds__(64)
void sort_kernel(const int* __restrict__ buckets, int* __restrict__ sticker,
                 int* __restrict__ pos) {
  __shared__ int lhist[64][129];
  __shared__ int starts[128];
  const int lane = threadIdx.x;
  const int br = blockIdx.x;
  const int* bk = buckets + (size_t)br * TLEN;
  int* st = sticker + (size_t)br * TLEN;
  int* ps = pos ? pos + (size_t)br * TLEN : nullptr;

  for (int i = 0; i < 128; ++i) lhist[lane][i] = 0;
  __syncthreads();
  for (int i = 0; i < 64; ++i) lhist[lane][bk[lane * 64 + i]]++;
  __syncthreads();

  int tot0 = 0, tot1 = 0;
  for (int c = 0; c < 64; ++c) {
    int v0 = lhist[c][lane];      lhist[c][lane]      = tot0; tot0 += v0;
    int v1 = lhist[c][lane + 64]; lhist[c][lane + 64] = tot1; tot1 += v1;
  }
  int s0 = tot0;
  for (int off = 1; off < 64; off <<= 1) {
    int u = __shfl_up(s0, off, 64);
    if (lane >= off) s0 += u;
  }
  int total0 = __shfl(s0, 63, 64);
  int s1 = tot1;
  for (int off = 1; off < 64; off <<= 1) {
    int u = __shfl_up(s1, off, 64);
    if (lane >= off) s1 += u;
  }
  starts[lane] = s0 - tot0;
  starts[lane + 64] = s1 - tot1 + total0;
  __syncthreads();

  for (int i = 0; i < 64; ++i) {
    int e = lane * 64 + i;
    int bb = bk[e];
    int c = lhist[lane][bb];
    lhist[lane][bb] = c + 1;
    int sp = starts[bb] + c;
    st[sp] = e;
    if (ps) ps[e] = sp;
  }
}

// ---------------------------------------------------------------------------
// MFMA attention per (bucket n, r, b_local): 64 Q rows x 128 keys, D=64.
// bf16x3 QK^T (Qh*Kh + Qh*Kl + Ql*Kh), softmax in f32, P split hi/lo,
// PV = Ph*V + Pl*V with V single bf16 (transposed in LDS).
// Verified round 5 (absmax 3.9e-3). Unchanged.
// ---------------------------------------------------------------------------
__global__ __launch_bounds__(256, 2)
void attn_kernel(const float* __restrict__ q, const float* __restrict__ k,
                 const float* __restrict__ v,
                 const int* __restrict__ sticker_q, const int* __restrict__ sticker_k,
                 float* __restrict__ so_buf, float* __restrict__ slse_buf,
                 int b_off) {
  __shared__ __align__(16) unsigned short Khi[128 * 64];  // 16 KB; later P_hi (64x128)
  __shared__ __align__(16) unsigned short Klo[128 * 64];  // 16 KB; later P_lo
  __shared__ __align__(16) unsigned short VtS[64 * 128];  // 16 KB, Vt[d][key]

  const int tid = threadIdx.x;
  const int w = tid >> 6;          // wave 0..3
  const int l = tid & 63;
  const int l15 = l & 15;
  const int qd = l >> 4;           // quad16 group 0..3
  const int n = blockIdx.x, r = blockIdx.y, bl = blockIdx.z;
  const int b = b_off + bl;
  const size_t brbase = ((size_t)b * NHASH + r) * TLEN;
  const size_t obase  = ((size_t)bl * NHASH + r) * TLEN;
  const int nprev = (n + NBUCK - 1) & (NBUCK - 1);

  const float* kb = k + (size_t)b * TLEN * DIM;
  const float* vb = v + (size_t)b * TLEN * DIM;
  const float* qb = q + (size_t)b * TLEN * DIM;

  // ---- stage K (hi/lo, row-major, granule-swizzled) ----
  for (int it = 0; it < 4; ++it) {
    int idx = it * 256 + tid;         // 1024 = 128 rows x 8 chunks(8 f32)
    int row = idx >> 3, gc = idx & 7;
    int srow = (row < 64) ? (nprev * 64 + row) : (n * 64 + (row - 64));
    int ik = sticker_k[brbase + srow];
    const float* src = kb + (size_t)ik * DIM + gc * 8;
    short8 h8, l8;
    split8(*(const float4*)src, *(const float4*)(src + 4), h8, l8);
    int o = (row << 6) + ((gc ^ (row & 7)) << 3);
    *(short8*)&Khi[o] = h8;
    *(short8*)&Klo[o] = l8;
  }
  // ---- stage V transposed: Vt[d][key], hi only ----
  for (int it = 0; it < 8; ++it) {
    int idx = it * 256 + tid;         // 2048 = 128 keys x 16 float4
    int key = idx >> 4, g4 = idx & 15;
    int srow = (key < 64) ? (nprev * 64 + key) : (n * 64 + (key - 64));
    int ik = sticker_k[brbase + srow];
    float4 vv = *(const float4*)(vb + (size_t)ik * DIM + g4 * 4);
    int kg = key >> 3, kr = key & 7;
#pragma unroll
    for (int e = 0; e < 4; ++e) {
      int d = g4 * 4 + e;
      float val = (e == 0) ? vv.x : (e == 1) ? vv.y : (e == 2) ? vv.z : vv.w;
      VtS[d * 128 + ((kg ^ (d & 15)) << 3) + kr] = bf16_rne(val);
    }
  }

  // ---- Q fragments from global (A-layout: m=l15, k=qd*8+j), scaled by 1/8 ----
  const int torig = sticker_q[brbase + n * 64 + w * 16 + l15];
  short8 Ahi[2], Alo[2];
#pragma unroll
  for (int ks = 0; ks < 2; ++ks) {
    const float* src = qb + (size_t)torig * DIM + ks * 32 + qd * 8;
    float4 q0 = *(const float4*)src;
    float4 q1 = *(const float4*)(src + 4);
    const float sc = 0.125f;
    q0.x *= sc; q0.y *= sc; q0.z *= sc; q0.w *= sc;
    q1.x *= sc; q1.y *= sc; q1.z *= sc; q1.w *= sc;
    split8(q0, q1, Ahi[ks], Alo[ks]);
  }
  __syncthreads();

  // ---- QK^T: S[16 x 128] per wave, bf16x3 ----
  float4v Sacc[8];
#pragma unroll
  for (int nt = 0; nt < 8; ++nt) {
    float4v z = {0.f, 0.f, 0.f, 0.f};
    Sacc[nt] = z;
#pragma unroll
    for (int ks = 0; ks < 2; ++ks) {
      int key = nt * 16 + l15;
      int gk = ks * 4 + qd;                       // granule 0..7
      int o = (key << 6) + ((gk ^ (key & 7)) << 3);
      short8 Bh = *(const short8*)&Khi[o];
      short8 Bl = *(const short8*)&Klo[o];
      Sacc[nt] = __builtin_amdgcn_mfma_f32_16x16x32_bf16(Ahi[ks], Bh, Sacc[nt], 0, 0, 0);
      Sacc[nt] = __builtin_amdgcn_mfma_f32_16x16x32_bf16(Alo[ks], Bh, Sacc[nt], 0, 0, 0);
      Sacc[nt] = __builtin_amdgcn_mfma_f32_16x16x32_bf16(Ahi[ks], Bl, Sacc[nt], 0, 0, 0);
    }
  }

  // ---- softmax over 128 cols; row = qd*4+i, col = nt*16 + l15 ----
  float lsev[4];
#pragma unroll
  for (int i = 0; i < 4; ++i) {
    float m = -INFINITY;
#pragma unroll
    for (int nt = 0; nt < 8; ++nt) m = fmaxf(m, Sacc[nt][i]);
    m = fmaxf(m, __shfl_xor(m, 1, 64));
    m = fmaxf(m, __shfl_xor(m, 2, 64));
    m = fmaxf(m, __shfl_xor(m, 4, 64));
    m = fmaxf(m, __shfl_xor(m, 8, 64));
    float Z = 0.f;
#pragma unroll
    for (int nt = 0; nt < 8; ++nt) {
      float e = __expf(Sacc[nt][i] - m);
      Sacc[nt][i] = e;
      Z += e;
    }
    Z += __shfl_xor(Z, 1, 64);
    Z += __shfl_xor(Z, 2, 64);
    Z += __shfl_xor(Z, 4, 64);
    Z += __shfl_xor(Z, 8, 64);
    float invZ = 1.0f / Z;
#pragma unroll
    for (int nt = 0; nt < 8; ++nt) Sacc[nt][i] *= invZ;
    lsev[i] = m + __logf(Z);
  }
  if (l15 == 0) {
#pragma unroll
    for (int i = 0; i < 4; ++i)
      slse_buf[brbase + n * 64 + w * 16 + qd * 4 + i] = lsev[i];
  }

  __syncthreads();   // all waves done reading Khi/Klo before P overwrites them

  // ---- write P (hi/lo) to LDS, 64 rows x 128 cols, granule-swizzled ----
  unsigned short* Phi = Khi;
  unsigned short* Plo = Klo;
#pragma unroll
  for (int nt = 0; nt < 8; ++nt) {
#pragma unroll
    for (int i = 0; i < 4; ++i) {
      int prow = w * 16 + qd * 4 + i;
      int col = nt * 16 + l15;
      float pv = Sacc[nt][i];
      unsigned short ph = bf16_rne(pv);
      unsigned short pl = bf16_rne(pv - bf16_to_f32(ph));
      int o = prow * 128 + (((col >> 3) ^ (prow & 15)) << 3) + (col & 7);
      Phi[o] = ph;
      Plo[o] = pl;
    }
  }
  // own-wave write->read (each wave reads only rows it wrote; DS ops in order)

  // ---- PV: O[16 x 64] per wave ----
  float4v Oacc[4];
#pragma unroll
  for (int dt = 0; dt < 4; ++dt) { float4v z = {0.f, 0.f, 0.f, 0.f}; Oacc[dt] = z; }
#pragma unroll
  for (int ks = 0; ks < 4; ++ks) {
    int arow = w * 16 + l15;
    int ga = (ks * 4 + qd) ^ (arow & 15);
    int ao = arow * 128 + (ga << 3);
    short8 Ph = *(const short8*)&Phi[ao];
    short8 Pl = *(const short8*)&Plo[ao];
#pragma unroll
    for (int dt = 0; dt < 4; ++dt) {
      int vrow = dt * 16 + l15;
      int gv = (ks * 4 + qd) ^ (vrow & 15);
      short8 Bv = *(const short8*)&VtS[vrow * 128 + (gv << 3)];
      Oacc[dt] = __builtin_amdgcn_mfma_f32_16x16x32_bf16(Ph, Bv, Oacc[dt], 0, 0, 0);
      Oacc[dt] = __builtin_amdgcn_mfma_f32_16x16x32_bf16(Pl, Bv, Oacc[dt], 0, 0, 0);
    }
  }

  // ---- epilogue: sorted-order store. D[row=qd*4+i][col=l15] per dt ----
#pragma unroll
  for (int dt = 0; dt < 4; ++dt) {
#pragma unroll
    for (int i = 0; i < 4; ++i) {
      int orow = n * 64 + w * 16 + qd * 4 + i;
      so_buf[(obase + orow) * DIM + dt * 16 + l15] = Oacc[dt][i];
    }
  }
}

// ---------------------------------------------------------------------------
// Combine the 8 hash rounds (gather via pos_q; unchanged, verified).
// ---------------------------------------------------------------------------
__global__ __launch_bounds__(256)
void combine_kernel(const float* __restrict__ so_buf, const float* __restrict__ slse_buf,
                    const int* __restrict__ pos_q, float* __restrict__ out, int b_off) {
  const size_t tid = (size_t)blockIdx.x * 256 + threadIdx.x;
  const size_t bt = tid >> 4;
  const int g = (int)(tid & 15);
  const size_t bl = bt >> 12;
  const size_t t = bt & 4095;
  const size_t b = b_off + bl;

  int pp[8];
  float l[8];
  float M = -INFINITY;
#pragma unroll
  for (int rr = 0; rr < 8; ++rr) {
    pp[rr] = pos_q[(b * NHASH + rr) * TLEN + t];
    l[rr] = slse_buf[(b * NHASH + rr) * TLEN + pp[rr]];
    M = fmaxf(M, l[rr]);
  }
  float Z = 0.f;
  float w[8];
#pragma unroll
  for (int rr = 0; rr < 8; ++rr) { w[rr] = __expf(l[rr] - M); Z += w[rr]; }
  const float invZ = 1.0f / Z;

  float4 s = make_float4(0.f, 0.f, 0.f, 0.f);
#pragma unroll
  for (int rr = 0; rr < 8; ++rr) {
    const float* op = so_buf + ((bl * NHASH + rr) * TLEN + (size_t)pp[rr]) * DIM + g * 4;
    float4 ov = *(const float4*)op;
    s.x = fmaf(w[rr], ov.x, s.x);
    s.y = fmaf(w[rr], ov.y, s.y);
    s.z = fmaf(w[rr], ov.z, s.z);
    s.w = fmaf(w[rr], ov.w, s.w);
  }
  s.x *= invZ; s.y *= invZ; s.z *= invZ; s.w *= invZ;
  *(float4*)(out + (b * TLEN + t) * DIM + g * 4) = s;
}

// ---------------------------------------------------------------------------
// Workspace layout (adaptive): stickers 8MB + pos 4MB + slse 4MB + shared
// region (buckets during hash/sort, so_buf CB*8MB during attn/combine).
// ---------------------------------------------------------------------------
extern "C" void kernel_launch(void* const* d_in, const int* in_sizes, int n_in,
                              void* d_out, int out_size, void* d_ws, size_t ws_size,
                              hipStream_t stream) {
  const float* q = (const float*)d_in[0];
  const float* k = (const float*)d_in[1];
  const float* v = (const float*)d_in[2];
  const float* proj = (const float*)d_in[3];
  float* out = (float*)d_out;

  char* ws = (char*)d_ws;
  const size_t MB = (size_t)1 << 20;
  int* sticker_q = (int*)(ws + 0 * MB);
  int* sticker_k = (int*)(ws + 4 * MB);
  int* pos_q     = (int*)(ws + 8 * MB);
  float* slse_buf = (float*)(ws + 12 * MB);
  int* buckets_q = (int*)(ws + 16 * MB);
  int* buckets_k = (int*)(ws + 20 * MB);
  float* so_buf  = (float*)(ws + 16 * MB);

  int CB = 32;
  while (CB > 1 && 16 * MB + (size_t)CB * 8 * MB > ws_size) CB >>= 1;

  hash_kernel<<<dim3(TLEN / 64, NHASH, BATCH), 256, 0, stream>>>(q, proj, buckets_q);
  hash_kernel<<<dim3(TLEN / 64, NHASH, BATCH), 256, 0, stream>>>(k, proj, buckets_k);
  sort_kernel<<<dim3(BATCH * NHASH), 64, 0, stream>>>(buckets_q, sticker_q, pos_q);
  sort_kernel<<<dim3(BATCH * NHASH), 64, 0, stream>>>(buckets_k, sticker_k, nullptr);

  for (int b_off = 0; b_off < BATCH; b_off += CB) {
    attn_kernel<<<dim3(NBUCK, NHASH, CB), 256, 0, stream>>>(
        q, k, v, sticker_q, sticker_k, so_buf, slse_buf, b_off);
    combine_kernel<<<dim3(CB * TLEN * 16 / 256), 256, 0, stream>>>(
        so_buf, slse_buf, pos_q, out, b_off);
  }
}

// Round 9
// 621.415 us; speedup vs baseline: 22.6814x; 1.3124x over previous
//
#include <hip/hip_runtime.h>
#include <math.h>

#define BATCH 32
#define TLEN  4096
#define DIM   64
#define NHASH 8
#define NBUCK 64   // n_buckets
#define BSIZE 64   // bucket size

typedef __attribute__((ext_vector_type(8))) short short8;
typedef __attribute__((ext_vector_type(4))) float float4v;

__device__ inline unsigned short bf16_rne(float x) {
  unsigned u = __float_as_uint(x);
  u += 0x7FFFu + ((u >> 16) & 1u);
  return (unsigned short)(u >> 16);
}
__device__ inline float bf16_to_f32(unsigned short h) {
  return __uint_as_float(((unsigned)h) << 16);
}

// ---------------------------------------------------------------------------
// Prep kernel (one-time, 8 blocks): transpose + bf16-split proj into
//   pjh/pjl[r][nn][d]  (bf16 hi/lo, GRANULE-SWIZZLED exactly as the hash
//                       kernel's MFMA B-frag reads expect)
//   proj_t[r][nn][d]   (exact f32, for the rare f64 fallback; L2-resident)
// Round-7 post-mortem: doing this transpose per hash block serialized on
// LDS bank 0 (128 B/lane write stride -> 32-way conflict, 1.9e7 conflicts).
// ---------------------------------------------------------------------------
__global__ __launch_bounds__(256)
void prep_kernel(const float* __restrict__ proj, unsigned short* __restrict__ pjh,
                 unsigned short* __restrict__ pjl, float* __restrict__ proj_t) {
  const int r = blockIdx.x;
  const int tid = threadIdx.x;
  for (int kk = 0; kk < 16; ++kk) {
    int idx = kk * 256 + tid;        // 4096 = 64d x 64n
    int d = idx >> 6, nn = idx & 63; // consecutive tid -> consecutive nn (coalesced read)
    float val = proj[d * 512 + r * 64 + nn];
    unsigned short hb = bf16_rne(val);
    unsigned short lb = bf16_rne(val - bf16_to_f32(hb));
    int g = d >> 3, e = d & 7;
    int o = (nn << 6) + ((g ^ (nn & 7)) << 3) + e;
    pjh[r * 4096 + o] = hb;
    pjl[r * 4096 + o] = lb;
    proj_t[r * 4096 + nn * 64 + d] = val;
  }
}

// ---------------------------------------------------------------------------
// MFMA hash kernel: colors[b,r,t] = argmax_n( concat(px, -px) ).
// bf16x4 MFMA dots, argmax via 16-lane shuffle reduction, exact f64
// cooperative fallback (reads proj_t/x from global) when the top-2 gap is
// inside E2 = 2.5e-4 * Sum|x|  -> decisions bit-identical to f64 argmax
// (validated rounds 2-7). Staging is 4 coalesced short8 copies/thread
// from the pre-swizzled global images (linear LDS writes, conflict-free).
// ---------------------------------------------------------------------------
__global__ __launch_bounds__(256, 2)
void hash_kernel(const float* __restrict__ x, const float* __restrict__ proj_t,
                 const unsigned short* __restrict__ pjh,
                 const unsigned short* __restrict__ pjl,
                 int* __restrict__ buckets) {
  __shared__ __align__(16) unsigned short pbh[64 * 64]; // 8 KB, pre-swizzled [n][d]
  __shared__ __align__(16) unsigned short pbl[64 * 64]; // 8 KB
  __shared__ float sxs[64];                             // per-row Sum|x|

  const int tid = threadIdx.x;
  const int w = tid >> 6;
  const int l = tid & 63;
  const int l15 = l & 15;
  const int qd = l >> 4;
  const int r = blockIdx.y, b = blockIdx.z;
  const int t0 = blockIdx.x << 6;

  // stage pre-swizzled proj images: linear copy, coalesced, conflict-free
  const unsigned short* gh = pjh + (size_t)r * 4096;
  const unsigned short* gl = pjl + (size_t)r * 4096;
#pragma unroll
  for (int it = 0; it < 2; ++it) {
    int idx = it * 256 + tid;        // 512 granules x 16 B = 8 KB each
    *(short8*)&pbh[idx * 8] = *(const short8*)&gh[idx * 8];
    *(short8*)&pbl[idx * 8] = *(const short8*)&gl[idx * 8];
  }

  // A-fragments: lane holds x[row m=l15][k = qd*8+j] for 2 k-steps; also Sum|x|
  const int trow_a = t0 + w * 16 + l15;
  const float* xra = x + ((size_t)b * TLEN + trow_a) * DIM;
  short8 Ahi[2], Alo[2];
  float sxp = 0.f;
#pragma unroll
  for (int ks = 0; ks < 2; ++ks) {
    float4 x0 = *(const float4*)(xra + ks * 32 + qd * 8);
    float4 x1 = *(const float4*)(xra + ks * 32 + qd * 8 + 4);
    sxp += fabsf(x0.x) + fabsf(x0.y) + fabsf(x0.z) + fabsf(x0.w)
         + fabsf(x1.x) + fabsf(x1.y) + fabsf(x1.z) + fabsf(x1.w);
    float v[8] = {x0.x, x0.y, x0.z, x0.w, x1.x, x1.y, x1.z, x1.w};
#pragma unroll
    for (int j = 0; j < 8; ++j) {
      unsigned short hb = bf16_rne(v[j]);
      Ahi[ks][j] = (short)hb;
      Alo[ks][j] = (short)bf16_rne(v[j] - bf16_to_f32(hb));
    }
  }
  // sum over qd (lanes l15+16*qd): xor 16, 32
  sxp += __shfl_xor(sxp, 16, 64);
  sxp += __shfl_xor(sxp, 32, 64);
  if (qd == 0) sxs[w * 16 + l15] = sxp;   // same-wave write->read (DS in order)
  __syncthreads();

  // MFMA: S[row][n], rows 16 per wave, n = nt*16 + l15, bf16x4
  float4v Sacc[4];
#pragma unroll
  for (int nt = 0; nt < 4; ++nt) {
    float4v z = {0.f, 0.f, 0.f, 0.f};
    Sacc[nt] = z;
#pragma unroll
    for (int ks = 0; ks < 2; ++ks) {
      int nn = nt * 16 + l15;
      int gk = ks * 4 + qd;
      int o = (nn << 6) + ((gk ^ (nn & 7)) << 3);
      short8 Bh = *(const short8*)&pbh[o];
      short8 Bl = *(const short8*)&pbl[o];
      Sacc[nt] = __builtin_amdgcn_mfma_f32_16x16x32_bf16(Ahi[ks], Bh, Sacc[nt], 0, 0, 0);
      Sacc[nt] = __builtin_amdgcn_mfma_f32_16x16x32_bf16(Alo[ks], Bh, Sacc[nt], 0, 0, 0);
      Sacc[nt] = __builtin_amdgcn_mfma_f32_16x16x32_bf16(Ahi[ks], Bl, Sacc[nt], 0, 0, 0);
      Sacc[nt] = __builtin_amdgcn_mfma_f32_16x16x32_bf16(Alo[ks], Bl, Sacc[nt], 0, 0, 0);
    }
  }

  // argmax per row i (C layout: row = qd*4+i, col = nt*16+l15)
#pragma unroll
  for (int i = 0; i < 4; ++i) {
    float bv = -INFINITY, sbv = -INFINITY;
    int bidx = 0;
#pragma unroll
    for (int nt = 0; nt < 4; ++nt) {
      int nn = nt * 16 + l15;
      float v = Sacc[nt][i];
      if (v > bv) { sbv = bv; bv = v; bidx = nn; }
      else        { sbv = fmaxf(sbv, v); }       // equality -> sbv==bv -> fallback
      float nv = -v;
      if (nv > bv) { sbv = bv; bv = nv; bidx = nn + 64; }
      else         { sbv = fmaxf(sbv, nv); }
    }
    // butterfly over the 16-lane col group
#pragma unroll
    for (int h = 1; h <= 8; h <<= 1) {
      float obv = __shfl_xor(bv, h, 64);
      float osb = __shfl_xor(sbv, h, 64);
      int   obi = __shfl_xor(bidx, h, 64);
      if (obv > bv)        { sbv = fmaxf(bv, osb); bv = obv; bidx = obi; }
      else if (obv == bv)  { sbv = bv; bidx = min(bidx, obi); }  // gap 0
      else                 { sbv = fmaxf(sbv, obv); }
    }
    const int trow = t0 + w * 16 + qd * 4 + i;
    const float Sx = sxs[w * 16 + qd * 4 + i];
    // group-uniform ambiguity test (bv/sbv identical across the 16 lanes)
    if (bv - sbv < 2.5e-4f * Sx) {
      // exact f64 cooperative re-decision: lane handles colors nt*16+l15;
      // proj_t is the exact f32 transposed copy (L2-resident, 128 KB)
      const float* xr2 = x + ((size_t)b * TLEN + trow) * DIM;
      const float* pt = proj_t + (size_t)r * 4096;
      double db = -1e300; int dbi = 0;
#pragma unroll
      for (int nt = 0; nt < 4; ++nt) {
        int nn = nt * 16 + l15;
        double s = 0.0;
        for (int d = 0; d < 64; ++d)
          s = fma((double)xr2[d], (double)pt[nn * 64 + d], s);
        if (s > db || (s == db && nn < dbi)) { db = s; dbi = nn; }
        double ns = -s; int nsi = nn + 64;
        if (ns > db || (ns == db && nsi < dbi)) { db = ns; dbi = nsi; }
      }
#pragma unroll
      for (int h = 1; h <= 8; h <<= 1) {
        double od = __shfl_xor(db, h, 64);
        int    oi = __shfl_xor(dbi, h, 64);
        if (od > db || (od == db && oi < dbi)) { db = od; dbi = oi; }
      }
      bidx = dbi;
    }
    if (l15 == 0)
      buckets[((size_t)b * NHASH + r) * TLEN + trow] = bidx;
  }
}

// ---------------------------------------------------------------------------
// Stable counting sort per (b,r) (unchanged, verified).
// ---------------------------------------------------------------------------
__global__ __launch_bounds__(64)
void sort_kernel(const int* __restrict__ buckets, int* __restrict__ sticker,
                 int* __restrict__ pos) {
  __shared__ int lhist[64][129];
  __shared__ int starts[128];
  const int lane = threadIdx.x;
  const int br = blockIdx.x;
  const int* bk = buckets + (size_t)br * TLEN;
  int* st = sticker + (size_t)br * TLEN;
  int* ps = pos ? pos + (size_t)br * TLEN : nullptr;

  for (int i = 0; i < 128; ++i) lhist[lane][i] = 0;
  __syncthreads();
  for (int i = 0; i < 64; ++i) lhist[lane][bk[lane * 64 + i]]++;
  __syncthreads();

  int tot0 = 0, tot1 = 0;
  for (int c = 0; c < 64; ++c) {
    int v0 = lhist[c][lane];      lhist[c][lane]      = tot0; tot0 += v0;
    int v1 = lhist[c][lane + 64]; lhist[c][lane + 64] = tot1; tot1 += v1;
  }
  int s0 = tot0;
  for (int off = 1; off < 64; off <<= 1) {
    int u = __shfl_up(s0, off, 64);
    if (lane >= off) s0 += u;
  }
  int total0 = __shfl(s0, 63, 64);
  int s1 = tot1;
  for (int off = 1; off < 64; off <<= 1) {
    int u = __shfl_up(s1, off, 64);
    if (lane >= off) s1 += u;
  }
  starts[lane] = s0 - tot0;
  starts[lane + 64] = s1 - tot1 + total0;
  __syncthreads();

  for (int i = 0; i < 64; ++i) {
    int e = lane * 64 + i;
    int bb = bk[e];
    int c = lhist[lane][bb];
    lhist[lane][bb] = c + 1;
    int sp = starts[bb] + c;
    st[sp] = e;
    if (ps) ps[e] = sp;
  }
}

// ---------------------------------------------------------------------------
// MFMA attention per (bucket n, r, b_local): 64 Q rows x 128 keys, D=64.
// bf16x3 QK^T (Qh*Kh + Qh*Kl + Ql*Kh), softmax in f32, P split hi/lo,
// PV = Ph*V + Pl*V with V single bf16 (transposed in LDS).
// Verified round 5 (absmax 3.9e-3). Unchanged.
// ---------------------------------------------------------------------------
__global__ __launch_bounds__(256, 2)
void attn_kernel(const float* __restrict__ q, const float* __restrict__ k,
                 const float* __restrict__ v,
                 const int* __restrict__ sticker_q, const int* __restrict__ sticker_k,
                 float* __restrict__ so_buf, float* __restrict__ slse_buf,
                 int b_off) {
  __shared__ __align__(16) unsigned short Khi[128 * 64];  // 16 KB; later P_hi (64x128)
  __shared__ __align__(16) unsigned short Klo[128 * 64];  // 16 KB; later P_lo
  __shared__ __align__(16) unsigned short VtS[64 * 128];  // 16 KB, Vt[d][key]

  const int tid = threadIdx.x;
  const int w = tid >> 6;          // wave 0..3
  const int l = tid & 63;
  const int l15 = l & 15;
  const int qd = l >> 4;           // quad16 group 0..3
  const int n = blockIdx.x, r = blockIdx.y, bl = blockIdx.z;
  const int b = b_off + bl;
  const size_t brbase = ((size_t)b * NHASH + r) * TLEN;
  const size_t obase  = ((size_t)bl * NHASH + r) * TLEN;
  const int nprev = (n + NBUCK - 1) & (NBUCK - 1);

  const float* kb = k + (size_t)b * TLEN * DIM;
  const float* vb = v + (size_t)b * TLEN * DIM;
  const float* qb = q + (size_t)b * TLEN * DIM;

  // ---- stage K (hi/lo, row-major, granule-swizzled) ----
  for (int it = 0; it < 4; ++it) {
    int idx = it * 256 + tid;         // 1024 = 128 rows x 8 chunks(8 f32)
    int row = idx >> 3, gc = idx & 7;
    int srow = (row < 64) ? (nprev * 64 + row) : (n * 64 + (row - 64));
    int ik = sticker_k[brbase + srow];
    const float* src = kb + (size_t)ik * DIM + gc * 8;
    float4 s0 = *(const float4*)src;
    float4 s1 = *(const float4*)(src + 4);
    short8 h8, l8;
    float vv[8] = {s0.x, s0.y, s0.z, s0.w, s1.x, s1.y, s1.z, s1.w};
#pragma unroll
    for (int j = 0; j < 8; ++j) {
      unsigned short hb = bf16_rne(vv[j]);
      h8[j] = (short)hb;
      l8[j] = (short)bf16_rne(vv[j] - bf16_to_f32(hb));
    }
    int o = (row << 6) + ((gc ^ (row & 7)) << 3);
    *(short8*)&Khi[o] = h8;
    *(short8*)&Klo[o] = l8;
  }
  // ---- stage V transposed: Vt[d][key], hi only ----
  for (int it = 0; it < 8; ++it) {
    int idx = it * 256 + tid;         // 2048 = 128 keys x 16 float4
    int key = idx >> 4, g4 = idx & 15;
    int srow = (key < 64) ? (nprev * 64 + key) : (n * 64 + (key - 64));
    int ik = sticker_k[brbase + srow];
    float4 vv = *(const float4*)(vb + (size_t)ik * DIM + g4 * 4);
    int kg = key >> 3, kr = key & 7;
#pragma unroll
    for (int e = 0; e < 4; ++e) {
      int d = g4 * 4 + e;
      float val = (e == 0) ? vv.x : (e == 1) ? vv.y : (e == 2) ? vv.z : vv.w;
      VtS[d * 128 + ((kg ^ (d & 15)) << 3) + kr] = bf16_rne(val);
    }
  }

  // ---- Q fragments from global (A-layout: m=l15, k=qd*8+j), scaled by 1/8 ----
  const int torig = sticker_q[brbase + n * 64 + w * 16 + l15];
  short8 Ahi[2], Alo[2];
#pragma unroll
  for (int ks = 0; ks < 2; ++ks) {
    const float* src = qb + (size_t)torig * DIM + ks * 32 + qd * 8;
    float4 q0 = *(const float4*)src;
    float4 q1 = *(const float4*)(src + 4);
    const float sc = 0.125f;
    float vv[8] = {q0.x * sc, q0.y * sc, q0.z * sc, q0.w * sc,
                   q1.x * sc, q1.y * sc, q1.z * sc, q1.w * sc};
#pragma unroll
    for (int j = 0; j < 8; ++j) {
      unsigned short hb = bf16_rne(vv[j]);
      Ahi[ks][j] = (short)hb;
      Alo[ks][j] = (short)bf16_rne(vv[j] - bf16_to_f32(hb));
    }
  }
  __syncthreads();

  // ---- QK^T: S[16 x 128] per wave, bf16x3 ----
  float4v Sacc[8];
#pragma unroll
  for (int nt = 0; nt < 8; ++nt) {
    float4v z = {0.f, 0.f, 0.f, 0.f};
    Sacc[nt] = z;
#pragma unroll
    for (int ks = 0; ks < 2; ++ks) {
      int key = nt * 16 + l15;
      int gk = ks * 4 + qd;                       // granule 0..7
      int o = (key << 6) + ((gk ^ (key & 7)) << 3);
      short8 Bh = *(const short8*)&Khi[o];
      short8 Bl = *(const short8*)&Klo[o];
      Sacc[nt] = __builtin_amdgcn_mfma_f32_16x16x32_bf16(Ahi[ks], Bh, Sacc[nt], 0, 0, 0);
      Sacc[nt] = __builtin_amdgcn_mfma_f32_16x16x32_bf16(Alo[ks], Bh, Sacc[nt], 0, 0, 0);
      Sacc[nt] = __builtin_amdgcn_mfma_f32_16x16x32_bf16(Ahi[ks], Bl, Sacc[nt], 0, 0, 0);
    }
  }

  // ---- softmax over 128 cols; row = qd*4+i, col = nt*16 + l15 ----
  float lsev[4];
#pragma unroll
  for (int i = 0; i < 4; ++i) {
    float m = -INFINITY;
#pragma unroll
    for (int nt = 0; nt < 8; ++nt) m = fmaxf(m, Sacc[nt][i]);
    m = fmaxf(m, __shfl_xor(m, 1, 64));
    m = fmaxf(m, __shfl_xor(m, 2, 64));
    m = fmaxf(m, __shfl_xor(m, 4, 64));
    m = fmaxf(m, __shfl_xor(m, 8, 64));
    float Z = 0.f;
#pragma unroll
    for (int nt = 0; nt < 8; ++nt) {
      float e = __expf(Sacc[nt][i] - m);
      Sacc[nt][i] = e;
      Z += e;
    }
    Z += __shfl_xor(Z, 1, 64);
    Z += __shfl_xor(Z, 2, 64);
    Z += __shfl_xor(Z, 4, 64);
    Z += __shfl_xor(Z, 8, 64);
    float invZ = 1.0f / Z;
#pragma unroll
    for (int nt = 0; nt < 8; ++nt) Sacc[nt][i] *= invZ;
    lsev[i] = m + __logf(Z);
  }
  if (l15 == 0) {
#pragma unroll
    for (int i = 0; i < 4; ++i)
      slse_buf[brbase + n * 64 + w * 16 + qd * 4 + i] = lsev[i];
  }

  __syncthreads();   // all waves done reading Khi/Klo before P overwrites them

  // ---- write P (hi/lo) to LDS, 64 rows x 128 cols, granule-swizzled ----
  unsigned short* Phi = Khi;
  unsigned short* Plo = Klo;
#pragma unroll
  for (int nt = 0; nt < 8; ++nt) {
#pragma unroll
    for (int i = 0; i < 4; ++i) {
      int prow = w * 16 + qd * 4 + i;
      int col = nt * 16 + l15;
      float pv = Sacc[nt][i];
      unsigned short ph = bf16_rne(pv);
      unsigned short pl = bf16_rne(pv - bf16_to_f32(ph));
      int o = prow * 128 + (((col >> 3) ^ (prow & 15)) << 3) + (col & 7);
      Phi[o] = ph;
      Plo[o] = pl;
    }
  }
  // own-wave write->read (each wave reads only rows it wrote; DS ops in order)

  // ---- PV: O[16 x 64] per wave ----
  float4v Oacc[4];
#pragma unroll
  for (int dt = 0; dt < 4; ++dt) { float4v z = {0.f, 0.f, 0.f, 0.f}; Oacc[dt] = z; }
#pragma unroll
  for (int ks = 0; ks < 4; ++ks) {
    int arow = w * 16 + l15;
    int ga = (ks * 4 + qd) ^ (arow & 15);
    int ao = arow * 128 + (ga << 3);
    short8 Ph = *(const short8*)&Phi[ao];
    short8 Pl = *(const short8*)&Plo[ao];
#pragma unroll
    for (int dt = 0; dt < 4; ++dt) {
      int vrow = dt * 16 + l15;
      int gv = (ks * 4 + qd) ^ (vrow & 15);
      short8 Bv = *(const short8*)&VtS[vrow * 128 + (gv << 3)];
      Oacc[dt] = __builtin_amdgcn_mfma_f32_16x16x32_bf16(Ph, Bv, Oacc[dt], 0, 0, 0);
      Oacc[dt] = __builtin_amdgcn_mfma_f32_16x16x32_bf16(Pl, Bv, Oacc[dt], 0, 0, 0);
    }
  }

  // ---- epilogue: sorted-order store. D[row=qd*4+i][col=l15] per dt ----
#pragma unroll
  for (int dt = 0; dt < 4; ++dt) {
#pragma unroll
    for (int i = 0; i < 4; ++i) {
      int orow = n * 64 + w * 16 + qd * 4 + i;
      so_buf[(obase + orow) * DIM + dt * 16 + l15] = Oacc[dt][i];
    }
  }
}

// ---------------------------------------------------------------------------
// Combine the 8 hash rounds (gather via pos_q; unchanged, verified).
// ---------------------------------------------------------------------------
__global__ __launch_bounds__(256)
void combine_kernel(const float* __restrict__ so_buf, const float* __restrict__ slse_buf,
                    const int* __restrict__ pos_q, float* __restrict__ out, int b_off) {
  const size_t tid = (size_t)blockIdx.x * 256 + threadIdx.x;
  const size_t bt = tid >> 4;
  const int g = (int)(tid & 15);
  const size_t bl = bt >> 12;
  const size_t t = bt & 4095;
  const size_t b = b_off + bl;

  int pp[8];
  float l[8];
  float M = -INFINITY;
#pragma unroll
  for (int rr = 0; rr < 8; ++rr) {
    pp[rr] = pos_q[(b * NHASH + rr) * TLEN + t];
    l[rr] = slse_buf[(b * NHASH + rr) * TLEN + pp[rr]];
    M = fmaxf(M, l[rr]);
  }
  float Z = 0.f;
  float w[8];
#pragma unroll
  for (int rr = 0; rr < 8; ++rr) { w[rr] = __expf(l[rr] - M); Z += w[rr]; }
  const float invZ = 1.0f / Z;

  float4 s = make_float4(0.f, 0.f, 0.f, 0.f);
#pragma unroll
  for (int rr = 0; rr < 8; ++rr) {
    const float* op = so_buf + ((bl * NHASH + rr) * TLEN + (size_t)pp[rr]) * DIM + g * 4;
    float4 ov = *(const float4*)op;
    s.x = fmaf(w[rr], ov.x, s.x);
    s.y = fmaf(w[rr], ov.y, s.y);
    s.z = fmaf(w[rr], ov.z, s.z);
    s.w = fmaf(w[rr], ov.w, s.w);
  }
  s.x *= invZ; s.y *= invZ; s.z *= invZ; s.w *= invZ;
  *(float4*)(out + (b * TLEN + t) * DIM + g * 4) = s;
}

// ---------------------------------------------------------------------------
// Workspace layout (adaptive):
//   [0,  4MB)  sticker_q      [4,  8MB)  sticker_k
//   [8, 12MB)  pos_q          [12,16MB)  slse_buf
//   [16MB, +64KB) pjh   (+64KB) pjl   (+128KB) proj_t   (prep outputs)
//   [17MB, ..) shared region:
//       hash/sort:  buckets_q (4MB) + buckets_k (4MB)
//       attn/combine: so_buf, CB*8MB
// ---------------------------------------------------------------------------
extern "C" void kernel_launch(void* const* d_in, const int* in_sizes, int n_in,
                              void* d_out, int out_size, void* d_ws, size_t ws_size,
                              hipStream_t stream) {
  const float* q = (const float*)d_in[0];
  const float* k = (const float*)d_in[1];
  const float* v = (const float*)d_in[2];
  const float* proj = (const float*)d_in[3];
  float* out = (float*)d_out;

  char* ws = (char*)d_ws;
  const size_t MB = (size_t)1 << 20;
  const size_t KB = (size_t)1 << 10;
  int* sticker_q = (int*)(ws + 0 * MB);
  int* sticker_k = (int*)(ws + 4 * MB);
  int* pos_q     = (int*)(ws + 8 * MB);
  float* slse_buf = (float*)(ws + 12 * MB);
  unsigned short* pjh = (unsigned short*)(ws + 16 * MB);
  unsigned short* pjl = (unsigned short*)(ws + 16 * MB + 64 * KB);
  float* proj_t  = (float*)(ws + 16 * MB + 128 * KB);
  int* buckets_q = (int*)(ws + 17 * MB);
  int* buckets_k = (int*)(ws + 21 * MB);
  float* so_buf  = (float*)(ws + 17 * MB);   // reuses buckets region after sorts

  int CB = 32;
  while (CB > 1 && 17 * MB + (size_t)CB * 8 * MB > ws_size) CB >>= 1;

  prep_kernel<<<dim3(NHASH), 256, 0, stream>>>(proj, pjh, pjl, proj_t);
  hash_kernel<<<dim3(TLEN / 64, NHASH, BATCH), 256, 0, stream>>>(q, proj_t, pjh, pjl, buckets_q);
  hash_kernel<<<dim3(TLEN / 64, NHASH, BATCH), 256, 0, stream>>>(k, proj_t, pjh, pjl, buckets_k);
  sort_kernel<<<dim3(BATCH * NHASH), 64, 0, stream>>>(buckets_q, sticker_q, pos_q);
  sort_kernel<<<dim3(BATCH * NHASH), 64, 0, stream>>>(buckets_k, sticker_k, nullptr);

  for (int b_off = 0; b_off < BATCH; b_off += CB) {
    attn_kernel<<<dim3(NBUCK, NHASH, CB), 256, 0, stream>>>(
        q, k, v, sticker_q, sticker_k, so_buf, slse_buf, b_off);
    combine_kernel<<<dim3(CB * TLEN * 16 / 256), 256, 0, stream>>>(
        so_buf, slse_buf, pos_q, out, b_off);
  }
}

// Round 10
// 586.919 us; speedup vs baseline: 24.0145x; 1.0588x over previous
//
#include <hip/hip_runtime.h>
#include <math.h>

#define BATCH 32
#define TLEN  4096
#define DIM   64
#define NHASH 8
#define NBUCK 64   // n_buckets
#define BSIZE 64   // bucket size

typedef __attribute__((ext_vector_type(8))) short short8;
typedef __attribute__((ext_vector_type(8))) unsigned short ushort8;
typedef __attribute__((ext_vector_type(4))) float float4v;

__device__ inline unsigned short bf16_rne(float x) {
  unsigned u = __float_as_uint(x);
  u += 0x7FFFu + ((u >> 16) & 1u);
  return (unsigned short)(u >> 16);
}
__device__ inline float bf16_to_f32(unsigned short h) {
  return __uint_as_float(((unsigned)h) << 16);
}

// ---------------------------------------------------------------------------
// Prep kernel (one-time, 8 blocks): transpose + bf16-split proj (verified r9).
// ---------------------------------------------------------------------------
__global__ __launch_bounds__(256)
void prep_kernel(const float* __restrict__ proj, unsigned short* __restrict__ pjh,
                 unsigned short* __restrict__ pjl, float* __restrict__ proj_t) {
  const int r = blockIdx.x;
  const int tid = threadIdx.x;
  for (int kk = 0; kk < 16; ++kk) {
    int idx = kk * 256 + tid;        // 4096 = 64d x 64n
    int d = idx >> 6, nn = idx & 63;
    float val = proj[d * 512 + r * 64 + nn];
    unsigned short hb = bf16_rne(val);
    unsigned short lb = bf16_rne(val - bf16_to_f32(hb));
    int g = d >> 3, e = d & 7;
    int o = (nn << 6) + ((g ^ (nn & 7)) << 3) + e;
    pjh[r * 4096 + o] = hb;
    pjl[r * 4096 + o] = lb;
    proj_t[r * 4096 + nn * 64 + d] = val;
  }
}

// ---------------------------------------------------------------------------
// Per-chunk bf16 split prepass (round-10): q -> qh/ql (pre-scaled 1/8),
// k -> kh/kl, v -> vh. Moves the per-element split out of attn (where each
// K row was converted 2x and each Q row 8x, dominating VALUBusy=57%).
// Memory-bound. blockIdx.y selects the array.
// ---------------------------------------------------------------------------
__global__ __launch_bounds__(256)
void convert_kernel(const float* __restrict__ q, const float* __restrict__ k,
                    const float* __restrict__ v,
                    unsigned short* __restrict__ qh, unsigned short* __restrict__ ql,
                    unsigned short* __restrict__ kh, unsigned short* __restrict__ kl,
                    unsigned short* __restrict__ vh, int b_off) {
  const size_t idx = (size_t)blockIdx.x * 256 + threadIdx.x;  // CB*T*D/8 chunks
  const int which = blockIdx.y;
  const size_t soff = ((size_t)b_off * TLEN * DIM) + idx * 8;
  const size_t doff = idx * 8;
  if (which == 0) {
    float4 a = *(const float4*)(q + soff);
    float4 b = *(const float4*)(q + soff + 4);
    float vv[8] = {a.x, a.y, a.z, a.w, b.x, b.y, b.z, b.w};
    ushort8 h8, l8;
#pragma unroll
    for (int j = 0; j < 8; ++j) {
      float s = vv[j] * 0.125f;
      unsigned short hb = bf16_rne(s);
      h8[j] = hb;
      l8[j] = bf16_rne(s - bf16_to_f32(hb));
    }
    *(ushort8*)(qh + doff) = h8;
    *(ushort8*)(ql + doff) = l8;
  } else if (which == 1) {
    float4 a = *(const float4*)(k + soff);
    float4 b = *(const float4*)(k + soff + 4);
    float vv[8] = {a.x, a.y, a.z, a.w, b.x, b.y, b.z, b.w};
    ushort8 h8, l8;
#pragma unroll
    for (int j = 0; j < 8; ++j) {
      unsigned short hb = bf16_rne(vv[j]);
      h8[j] = hb;
      l8[j] = bf16_rne(vv[j] - bf16_to_f32(hb));
    }
    *(ushort8*)(kh + doff) = h8;
    *(ushort8*)(kl + doff) = l8;
  } else {
    float4 a = *(const float4*)(v + soff);
    float4 b = *(const float4*)(v + soff + 4);
    float vv[8] = {a.x, a.y, a.z, a.w, b.x, b.y, b.z, b.w};
    ushort8 h8;
#pragma unroll
    for (int j = 0; j < 8; ++j) h8[j] = bf16_rne(vv[j]);
    *(ushort8*)(vh + doff) = h8;
  }
}

// ---------------------------------------------------------------------------
// MFMA hash kernel (verified r9, unchanged): bf16x4 MFMA dots + exact f64
// cooperative fallback inside the rigorous margin -> decisions bit-identical
// to f64 argmax.
// ---------------------------------------------------------------------------
__global__ __launch_bounds__(256, 2)
void hash_kernel(const float* __restrict__ x, const float* __restrict__ proj_t,
                 const unsigned short* __restrict__ pjh,
                 const unsigned short* __restrict__ pjl,
                 int* __restrict__ buckets) {
  __shared__ __align__(16) unsigned short pbh[64 * 64];
  __shared__ __align__(16) unsigned short pbl[64 * 64];
  __shared__ float sxs[64];

  const int tid = threadIdx.x;
  const int w = tid >> 6;
  const int l = tid & 63;
  const int l15 = l & 15;
  const int qd = l >> 4;
  const int r = blockIdx.y, b = blockIdx.z;
  const int t0 = blockIdx.x << 6;

  const unsigned short* gh = pjh + (size_t)r * 4096;
  const unsigned short* gl = pjl + (size_t)r * 4096;
#pragma unroll
  for (int it = 0; it < 2; ++it) {
    int idx = it * 256 + tid;
    *(short8*)&pbh[idx * 8] = *(const short8*)&gh[idx * 8];
    *(short8*)&pbl[idx * 8] = *(const short8*)&gl[idx * 8];
  }

  const int trow_a = t0 + w * 16 + l15;
  const float* xra = x + ((size_t)b * TLEN + trow_a) * DIM;
  short8 Ahi[2], Alo[2];
  float sxp = 0.f;
#pragma unroll
  for (int ks = 0; ks < 2; ++ks) {
    float4 x0 = *(const float4*)(xra + ks * 32 + qd * 8);
    float4 x1 = *(const float4*)(xra + ks * 32 + qd * 8 + 4);
    sxp += fabsf(x0.x) + fabsf(x0.y) + fabsf(x0.z) + fabsf(x0.w)
         + fabsf(x1.x) + fabsf(x1.y) + fabsf(x1.z) + fabsf(x1.w);
    float v[8] = {x0.x, x0.y, x0.z, x0.w, x1.x, x1.y, x1.z, x1.w};
#pragma unroll
    for (int j = 0; j < 8; ++j) {
      unsigned short hb = bf16_rne(v[j]);
      Ahi[ks][j] = (short)hb;
      Alo[ks][j] = (short)bf16_rne(v[j] - bf16_to_f32(hb));
    }
  }
  sxp += __shfl_xor(sxp, 16, 64);
  sxp += __shfl_xor(sxp, 32, 64);
  if (qd == 0) sxs[w * 16 + l15] = sxp;
  __syncthreads();

  float4v Sacc[4];
#pragma unroll
  for (int nt = 0; nt < 4; ++nt) {
    float4v z = {0.f, 0.f, 0.f, 0.f};
    Sacc[nt] = z;
#pragma unroll
    for (int ks = 0; ks < 2; ++ks) {
      int nn = nt * 16 + l15;
      int gk = ks * 4 + qd;
      int o = (nn << 6) + ((gk ^ (nn & 7)) << 3);
      short8 Bh = *(const short8*)&pbh[o];
      short8 Bl = *(const short8*)&pbl[o];
      Sacc[nt] = __builtin_amdgcn_mfma_f32_16x16x32_bf16(Ahi[ks], Bh, Sacc[nt], 0, 0, 0);
      Sacc[nt] = __builtin_amdgcn_mfma_f32_16x16x32_bf16(Alo[ks], Bh, Sacc[nt], 0, 0, 0);
      Sacc[nt] = __builtin_amdgcn_mfma_f32_16x16x32_bf16(Ahi[ks], Bl, Sacc[nt], 0, 0, 0);
      Sacc[nt] = __builtin_amdgcn_mfma_f32_16x16x32_bf16(Alo[ks], Bl, Sacc[nt], 0, 0, 0);
    }
  }

#pragma unroll
  for (int i = 0; i < 4; ++i) {
    float bv = -INFINITY, sbv = -INFINITY;
    int bidx = 0;
#pragma unroll
    for (int nt = 0; nt < 4; ++nt) {
      int nn = nt * 16 + l15;
      float v = Sacc[nt][i];
      if (v > bv) { sbv = bv; bv = v; bidx = nn; }
      else        { sbv = fmaxf(sbv, v); }
      float nv = -v;
      if (nv > bv) { sbv = bv; bv = nv; bidx = nn + 64; }
      else         { sbv = fmaxf(sbv, nv); }
    }
#pragma unroll
    for (int h = 1; h <= 8; h <<= 1) {
      float obv = __shfl_xor(bv, h, 64);
      float osb = __shfl_xor(sbv, h, 64);
      int   obi = __shfl_xor(bidx, h, 64);
      if (obv > bv)        { sbv = fmaxf(bv, osb); bv = obv; bidx = obi; }
      else if (obv == bv)  { sbv = bv; bidx = min(bidx, obi); }
      else                 { sbv = fmaxf(sbv, obv); }
    }
    const int trow = t0 + w * 16 + qd * 4 + i;
    const float Sx = sxs[w * 16 + qd * 4 + i];
    if (bv - sbv < 2.5e-4f * Sx) {
      const float* xr2 = x + ((size_t)b * TLEN + trow) * DIM;
      const float* pt = proj_t + (size_t)r * 4096;
      double db = -1e300; int dbi = 0;
#pragma unroll
      for (int nt = 0; nt < 4; ++nt) {
        int nn = nt * 16 + l15;
        double s = 0.0;
        for (int d = 0; d < 64; ++d)
          s = fma((double)xr2[d], (double)pt[nn * 64 + d], s);
        if (s > db || (s == db && nn < dbi)) { db = s; dbi = nn; }
        double ns = -s; int nsi = nn + 64;
        if (ns > db || (ns == db && nsi < dbi)) { db = ns; dbi = nsi; }
      }
#pragma unroll
      for (int h = 1; h <= 8; h <<= 1) {
        double od = __shfl_xor(db, h, 64);
        int    oi = __shfl_xor(dbi, h, 64);
        if (od > db || (od == db && oi < dbi)) { db = od; dbi = oi; }
      }
      bidx = dbi;
    }
    if (l15 == 0)
      buckets[((size_t)b * NHASH + r) * TLEN + trow] = bidx;
  }
}

// ---------------------------------------------------------------------------
// Stable counting sort per (b,r) (unchanged, verified).
// ---------------------------------------------------------------------------
__global__ __launch_bounds__(64)
void sort_kernel(const int* __restrict__ buckets, int* __restrict__ sticker,
                 int* __restrict__ pos) {
  __shared__ int lhist[64][129];
  __shared__ int starts[128];
  const int lane = threadIdx.x;
  const int br = blockIdx.x;
  const int* bk = buckets + (size_t)br * TLEN;
  int* st = sticker + (size_t)br * TLEN;
  int* ps = pos ? pos + (size_t)br * TLEN : nullptr;

  for (int i = 0; i < 128; ++i) lhist[lane][i] = 0;
  __syncthreads();
  for (int i = 0; i < 64; ++i) lhist[lane][bk[lane * 64 + i]]++;
  __syncthreads();

  int tot0 = 0, tot1 = 0;
  for (int c = 0; c < 64; ++c) {
    int v0 = lhist[c][lane];      lhist[c][lane]      = tot0; tot0 += v0;
    int v1 = lhist[c][lane + 64]; lhist[c][lane + 64] = tot1; tot1 += v1;
  }
  int s0 = tot0;
  for (int off = 1; off < 64; off <<= 1) {
    int u = __shfl_up(s0, off, 64);
    if (lane >= off) s0 += u;
  }
  int total0 = __shfl(s0, 63, 64);
  int s1 = tot1;
  for (int off = 1; off < 64; off <<= 1) {
    int u = __shfl_up(s1, off, 64);
    if (lane >= off) s1 += u;
  }
  starts[lane] = s0 - tot0;
  starts[lane + 64] = s1 - tot1 + total0;
  __syncthreads();

  for (int i = 0; i < 64; ++i) {
    int e = lane * 64 + i;
    int bb = bk[e];
    int c = lhist[lane][bb];
    lhist[lane][bb] = c + 1;
    int sp = starts[bb] + c;
    st[sp] = e;
    if (ps) ps[e] = sp;
  }
}

// ---------------------------------------------------------------------------
// MFMA attention (round-10): staging reads pre-split bf16 arrays (zero
// conversion VALU), V-transpose writes are KEY-MAJOR across lanes (64
// consecutive keys, fixed d per step -> 2 lanes/bank = conflict-free).
// Output stored to so_buf as bf16 (halves write + combine-gather traffic).
// Math identical to the r5-verified kernel: bf16x3 QK, f32 softmax,
// P hi/lo x V(bf16) PV.
// ---------------------------------------------------------------------------
__global__ __launch_bounds__(256, 2)
void attn_kernel(const unsigned short* __restrict__ qh, const unsigned short* __restrict__ ql,
                 const unsigned short* __restrict__ kh, const unsigned short* __restrict__ kl,
                 const unsigned short* __restrict__ vh,
                 const int* __restrict__ sticker_q, const int* __restrict__ sticker_k,
                 unsigned short* __restrict__ so_buf, float* __restrict__ slse_buf,
                 int b_off) {
  __shared__ __align__(16) unsigned short Khi[128 * 64];  // 16 KB; later P_hi (64x128)
  __shared__ __align__(16) unsigned short Klo[128 * 64];  // 16 KB; later P_lo
  __shared__ __align__(16) unsigned short VtS[64 * 128];  // 16 KB, Vt[d][key]

  const int tid = threadIdx.x;
  const int w = tid >> 6;
  const int l = tid & 63;
  const int l15 = l & 15;
  const int qd = l >> 4;
  const int n = blockIdx.x, r = blockIdx.y, bl = blockIdx.z;
  const int b = b_off + bl;
  const size_t brbase = ((size_t)b * NHASH + r) * TLEN;
  const size_t obase  = ((size_t)bl * NHASH + r) * TLEN;
  const int nprev = (n + NBUCK - 1) & (NBUCK - 1);

  // ---- stage K hi/lo: pure short8 copies, b128 phase-serialized (no conflicts)
  for (int it = 0; it < 4; ++it) {
    int idx = it * 256 + tid;         // 1024 = 128 rows x 8 granules
    int row = idx >> 3, gc = idx & 7;
    int srow = (row < 64) ? (nprev * 64 + row) : (n * 64 + (row - 64));
    int ik = sticker_k[brbase + srow];
    size_t src = ((size_t)bl * TLEN + ik) * DIM + gc * 8;
    int o = (row << 6) + ((gc ^ (row & 7)) << 3);
    *(short8*)&Khi[o] = *(const short8*)(kh + src);
    *(short8*)&Klo[o] = *(const short8*)(kl + src);
  }
  // ---- stage V transposed, key-major lanes: step e writes fixed d,
  //      64 consecutive keys -> 2-way bank aliasing (free)
  for (int it = 0; it < 4; ++it) {
    int idx = it * 256 + tid;         // 1024 = 128 keys x 8 d-groups
    int key = idx & 127, dg = idx >> 7;
    int srow = (key < 64) ? (nprev * 64 + key) : (n * 64 + (key - 64));
    int ik = sticker_k[brbase + srow];
    ushort8 vv = *(const ushort8*)(vh + ((size_t)bl * TLEN + ik) * DIM + dg * 8);
    int kg = key >> 3, kr = key & 7;
#pragma unroll
    for (int e = 0; e < 8; ++e) {
      int d = dg * 8 + e;
      VtS[d * 128 + ((kg ^ (d & 15)) << 3) + kr] = vv[e];
    }
  }

  // ---- Q fragments: direct short8 loads (pre-scaled, pre-split)
  const int torig = sticker_q[brbase + n * 64 + w * 16 + l15];
  short8 Ahi[2], Alo[2];
#pragma unroll
  for (int ks = 0; ks < 2; ++ks) {
    size_t src = ((size_t)bl * TLEN + torig) * DIM + ks * 32 + qd * 8;
    Ahi[ks] = *(const short8*)(qh + src);
    Alo[ks] = *(const short8*)(ql + src);
  }
  __syncthreads();

  // ---- QK^T: S[16 x 128] per wave, bf16x3 ----
  float4v Sacc[8];
#pragma unroll
  for (int nt = 0; nt < 8; ++nt) {
    float4v z = {0.f, 0.f, 0.f, 0.f};
    Sacc[nt] = z;
#pragma unroll
    for (int ks = 0; ks < 2; ++ks) {
      int key = nt * 16 + l15;
      int gk = ks * 4 + qd;
      int o = (key << 6) + ((gk ^ (key & 7)) << 3);
      short8 Bh = *(const short8*)&Khi[o];
      short8 Bl = *(const short8*)&Klo[o];
      Sacc[nt] = __builtin_amdgcn_mfma_f32_16x16x32_bf16(Ahi[ks], Bh, Sacc[nt], 0, 0, 0);
      Sacc[nt] = __builtin_amdgcn_mfma_f32_16x16x32_bf16(Alo[ks], Bh, Sacc[nt], 0, 0, 0);
      Sacc[nt] = __builtin_amdgcn_mfma_f32_16x16x32_bf16(Ahi[ks], Bl, Sacc[nt], 0, 0, 0);
    }
  }

  // ---- softmax over 128 cols; row = qd*4+i, col = nt*16 + l15 ----
  float lsev[4];
#pragma unroll
  for (int i = 0; i < 4; ++i) {
    float m = -INFINITY;
#pragma unroll
    for (int nt = 0; nt < 8; ++nt) m = fmaxf(m, Sacc[nt][i]);
    m = fmaxf(m, __shfl_xor(m, 1, 64));
    m = fmaxf(m, __shfl_xor(m, 2, 64));
    m = fmaxf(m, __shfl_xor(m, 4, 64));
    m = fmaxf(m, __shfl_xor(m, 8, 64));
    float Z = 0.f;
#pragma unroll
    for (int nt = 0; nt < 8; ++nt) {
      float e = __expf(Sacc[nt][i] - m);
      Sacc[nt][i] = e;
      Z += e;
    }
    Z += __shfl_xor(Z, 1, 64);
    Z += __shfl_xor(Z, 2, 64);
    Z += __shfl_xor(Z, 4, 64);
    Z += __shfl_xor(Z, 8, 64);
    float invZ = 1.0f / Z;
#pragma unroll
    for (int nt = 0; nt < 8; ++nt) Sacc[nt][i] *= invZ;
    lsev[i] = m + __logf(Z);
  }
  if (l15 == 0) {
#pragma unroll
    for (int i = 0; i < 4; ++i)
      slse_buf[brbase + n * 64 + w * 16 + qd * 4 + i] = lsev[i];
  }

  __syncthreads();   // all waves done reading Khi/Klo before P overwrites them

  // ---- write P (hi/lo) to LDS, granule-swizzled ----
  unsigned short* Phi = Khi;
  unsigned short* Plo = Klo;
#pragma unroll
  for (int nt = 0; nt < 8; ++nt) {
#pragma unroll
    for (int i = 0; i < 4; ++i) {
      int prow = w * 16 + qd * 4 + i;
      int col = nt * 16 + l15;
      float pv = Sacc[nt][i];
      unsigned short ph = bf16_rne(pv);
      unsigned short pl = bf16_rne(pv - bf16_to_f32(ph));
      int o = prow * 128 + (((col >> 3) ^ (prow & 15)) << 3) + (col & 7);
      Phi[o] = ph;
      Plo[o] = pl;
    }
  }

  // ---- PV: O[16 x 64] per wave ----
  float4v Oacc[4];
#pragma unroll
  for (int dt = 0; dt < 4; ++dt) { float4v z = {0.f, 0.f, 0.f, 0.f}; Oacc[dt] = z; }
#pragma unroll
  for (int ks = 0; ks < 4; ++ks) {
    int arow = w * 16 + l15;
    int ga = (ks * 4 + qd) ^ (arow & 15);
    int ao = arow * 128 + (ga << 3);
    short8 Ph = *(const short8*)&Phi[ao];
    short8 Pl = *(const short8*)&Plo[ao];
#pragma unroll
    for (int dt = 0; dt < 4; ++dt) {
      int vrow = dt * 16 + l15;
      int gv = (ks * 4 + qd) ^ (vrow & 15);
      short8 Bv = *(const short8*)&VtS[vrow * 128 + (gv << 3)];
      Oacc[dt] = __builtin_amdgcn_mfma_f32_16x16x32_bf16(Ph, Bv, Oacc[dt], 0, 0, 0);
      Oacc[dt] = __builtin_amdgcn_mfma_f32_16x16x32_bf16(Pl, Bv, Oacc[dt], 0, 0, 0);
    }
  }

  // ---- epilogue: sorted-order bf16 store ----
#pragma unroll
  for (int dt = 0; dt < 4; ++dt) {
#pragma unroll
    for (int i = 0; i < 4; ++i) {
      int orow = n * 64 + w * 16 + qd * 4 + i;
      so_buf[(obase + orow) * DIM + dt * 16 + l15] = bf16_rne(Oacc[dt][i]);
    }
  }
}

// ---------------------------------------------------------------------------
// Combine the 8 hash rounds (gather via pos_q); so_buf now bf16.
// Thread per (b,t, 8-element granule g in 0..7).
// ---------------------------------------------------------------------------
__global__ __launch_bounds__(256)
void combine_kernel(const unsigned short* __restrict__ so_buf,
                    const float* __restrict__ slse_buf,
                    const int* __restrict__ pos_q, float* __restrict__ out, int b_off) {
  const size_t tid = (size_t)blockIdx.x * 256 + threadIdx.x;  // CB*T*8
  const size_t bt = tid >> 3;
  const int g = (int)(tid & 7);
  const size_t bl = bt >> 12;
  const size_t t = bt & 4095;
  const size_t b = b_off + bl;

  int pp[8];
  float l[8];
  float M = -INFINITY;
#pragma unroll
  for (int rr = 0; rr < 8; ++rr) {
    pp[rr] = pos_q[(b * NHASH + rr) * TLEN + t];
    l[rr] = slse_buf[(b * NHASH + rr) * TLEN + pp[rr]];
    M = fmaxf(M, l[rr]);
  }
  float Z = 0.f;
  float w[8];
#pragma unroll
  for (int rr = 0; rr < 8; ++rr) { w[rr] = __expf(l[rr] - M); Z += w[rr]; }
  const float invZ = 1.0f / Z;

  float s[8] = {0.f, 0.f, 0.f, 0.f, 0.f, 0.f, 0.f, 0.f};
#pragma unroll
  for (int rr = 0; rr < 8; ++rr) {
    ushort8 ov = *(const ushort8*)(so_buf +
        ((bl * NHASH + rr) * TLEN + (size_t)pp[rr]) * DIM + g * 8);
#pragma unroll
    for (int j = 0; j < 8; ++j)
      s[j] = fmaf(w[rr], bf16_to_f32(ov[j]), s[j]);
  }
  float* op = out + (b * TLEN + t) * DIM + g * 8;
  float4 o0 = make_float4(s[0] * invZ, s[1] * invZ, s[2] * invZ, s[3] * invZ);
  float4 o1 = make_float4(s[4] * invZ, s[5] * invZ, s[6] * invZ, s[7] * invZ);
  *(float4*)op = o0;
  *(float4*)(op + 4) = o1;
}

// ---------------------------------------------------------------------------
// Workspace layout (adaptive):
//   [0,4) sticker_q  [4,8) sticker_k  [8,12) pos_q  [12,16) slse   (MB)
//   [16MB,+192KB) pjh/pjl/proj_t (prep outputs)
//   [17,21) buckets_q  [21,25) buckets_k            (hash/sort phase)
//   chunk region from 17MB (reused after sorts):
//     so_buf bf16 CB*4MB | qh,ql,kh,kl,vh bf16 CB*0.5MB each
//   total = 17 + 6.5*CB MB;  CB in {32..1} largest fitting (min 23.5 MB).
// ---------------------------------------------------------------------------
extern "C" void kernel_launch(void* const* d_in, const int* in_sizes, int n_in,
                              void* d_out, int out_size, void* d_ws, size_t ws_size,
                              hipStream_t stream) {
  const float* q = (const float*)d_in[0];
  const float* k = (const float*)d_in[1];
  const float* v = (const float*)d_in[2];
  const float* proj = (const float*)d_in[3];
  float* out = (float*)d_out;

  char* ws = (char*)d_ws;
  const size_t MB = (size_t)1 << 20;
  const size_t KB = (size_t)1 << 10;
  int* sticker_q = (int*)(ws + 0 * MB);
  int* sticker_k = (int*)(ws + 4 * MB);
  int* pos_q     = (int*)(ws + 8 * MB);
  float* slse_buf = (float*)(ws + 12 * MB);
  unsigned short* pjh = (unsigned short*)(ws + 16 * MB);
  unsigned short* pjl = (unsigned short*)(ws + 16 * MB + 64 * KB);
  float* proj_t  = (float*)(ws + 16 * MB + 128 * KB);
  int* buckets_q = (int*)(ws + 17 * MB);
  int* buckets_k = (int*)(ws + 21 * MB);

  int CB = 32;
  while (CB > 1 && 17 * MB + (size_t)CB * 13 * MB / 2 > ws_size) CB >>= 1;

  char* chunk = ws + 17 * MB;
  unsigned short* so_buf = (unsigned short*)chunk;
  unsigned short* qh = (unsigned short*)(chunk + (size_t)CB * 4 * MB);
  unsigned short* ql = (unsigned short*)(chunk + (size_t)CB * 9 * MB / 2);
  unsigned short* kh = (unsigned short*)(chunk + (size_t)CB * 5 * MB);
  unsigned short* kl = (unsigned short*)(chunk + (size_t)CB * 11 * MB / 2);
  unsigned short* vh = (unsigned short*)(chunk + (size_t)CB * 6 * MB);

  prep_kernel<<<dim3(NHASH), 256, 0, stream>>>(proj, pjh, pjl, proj_t);
  hash_kernel<<<dim3(TLEN / 64, NHASH, BATCH), 256, 0, stream>>>(q, proj_t, pjh, pjl, buckets_q);
  hash_kernel<<<dim3(TLEN / 64, NHASH, BATCH), 256, 0, stream>>>(k, proj_t, pjh, pjl, buckets_k);
  sort_kernel<<<dim3(BATCH * NHASH), 64, 0, stream>>>(buckets_q, sticker_q, pos_q);
  sort_kernel<<<dim3(BATCH * NHASH), 64, 0, stream>>>(buckets_k, sticker_k, nullptr);

  for (int b_off = 0; b_off < BATCH; b_off += CB) {
    convert_kernel<<<dim3(CB * 128, 3), 256, 0, stream>>>(q, k, v, qh, ql, kh, kl, vh, b_off);
    attn_kernel<<<dim3(NBUCK, NHASH, CB), 256, 0, stream>>>(
        qh, ql, kh, kl, vh, sticker_q, sticker_k, so_buf, slse_buf, b_off);
    combine_kernel<<<dim3(CB * TLEN * 8 / 256), 256, 0, stream>>>(
        so_buf, slse_buf, pos_q, out, b_off);
  }
}